// Round 2
// baseline (498.660 us; speedup 1.0000x reference)
//
#include <hip/hip_runtime.h>
#include <cstdint>
#include <math.h>

typedef unsigned short us;
typedef __attribute__((ext_vector_type(8))) __bf16 bf16x8;
typedef __attribute__((ext_vector_type(8))) unsigned short ushort8;
typedef __attribute__((ext_vector_type(4))) float f32x4;

__device__ __forceinline__ us f2bf(float x){
  union { float f; unsigned int u; } v; v.f = x;
  unsigned int r = v.u + 0x7FFFu + ((v.u >> 16) & 1u);   // RNE
  return (us)(r >> 16);
}
__device__ __forceinline__ float b2f(us u){
  union { unsigned int u; float f; } v; v.u = ((unsigned int)u) << 16; return v.f;
}
__device__ __forceinline__ void split2(float x, us& hi, us& lo){
  hi = f2bf(x); lo = f2bf(x - b2f(hi));
}
__device__ __forceinline__ f32x4 fzero(){ f32x4 v; v.x=0.f; v.y=0.f; v.z=0.f; v.w=0.f; return v; }
__device__ __forceinline__ f32x4 mfma16(bf16x8 a, bf16x8 b, f32x4 c){
  return __builtin_amdgcn_mfma_f32_16x16x32_bf16(a, b, c, 0, 0, 0);
}
__device__ __forceinline__ void gload_lds16(const void* g, void* l){
  __builtin_amdgcn_global_load_lds(
      (const __attribute__((address_space(1))) unsigned int*)(uintptr_t)g,
      (__attribute__((address_space(3))) unsigned int*)(uintptr_t)l,
      16, 0, 0);
}

// ---------------- 1: fp32 -> bf16 hi/lo split of inputs ----------------
__global__ __launch_bounds__(256) void k_convx(const float* __restrict__ xq,
                                               const float* __restrict__ xkv,
                                               us* __restrict__ qhi, us* __restrict__ qlo,
                                               us* __restrict__ kvhi, us* __restrict__ kvlo)
{
  int i = blockIdx.x * 256 + threadIdx.x;   // float4 units, 2M total
  const float* src; us *dh, *dl;
  if (i < 1048576) { src = xq  + (size_t)i*4;            dh = qhi  + (size_t)i*4;            dl = qlo  + (size_t)i*4; }
  else             { src = xkv + (size_t)(i-1048576)*4;  dh = kvhi + (size_t)(i-1048576)*4;  dl = kvlo + (size_t)(i-1048576)*4; }
  f32x4 v = *(const f32x4*)src;
  us h0,l0,h1,l1,h2,l2,h3,l3;
  split2(v.x,h0,l0); split2(v.y,h1,l1); split2(v.z,h2,l2); split2(v.w,h3,l3);
  dh[0]=h0; dh[1]=h1; dh[2]=h2; dh[3]=h3;
  dl[0]=l0; dl[1]=l1; dl[2]=l2; dl[3]=l3;
}

// ---------------- 2: weight transpose + hi/lo split: Wt[n][k] ----------------
__global__ __launch_bounds__(256) void k_convw(const float* w0, const float* w1, const float* w2,
                                               const float* w3, const float* w4, const float* w5,
                                               us* __restrict__ wt)
{
  __shared__ float tile[32][33];
  int z = blockIdx.z;
  const float* W = (z==0)?w0:(z==1)?w1:(z==2)?w2:(z==3)?w3:(z==4)?w4:w5;
  us* dst_hi = wt + (size_t)z * 2097152;
  us* dst_lo = dst_hi + 1048576;
  int n0 = blockIdx.x * 32, k0 = blockIdx.y * 32;
  int c = threadIdx.x & 31, r = threadIdx.x >> 5;
#pragma unroll
  for (int i = 0; i < 4; i++)
    tile[r + i*8][c] = W[(size_t)(k0 + r + i*8)*1024 + n0 + c];
  __syncthreads();
#pragma unroll
  for (int i = 0; i < 4; i++){
    int nn = r + i*8;
    us h,l; split2(tile[c][nn], h, l);
    dst_hi[(size_t)(n0 + nn)*1024 + k0 + c] = h;
    dst_lo[(size_t)(n0 + nn)*1024 + k0 + c] = l;
  }
}

// ---------------- 3: layernorm(rel_emb) -> bf16 hi/lo ----------------
__global__ __launch_bounds__(256) void k_lnrel(const float* __restrict__ rel,
                                               const float* __restrict__ g,
                                               const float* __restrict__ b,
                                               us* __restrict__ out_hi,
                                               us* __restrict__ out_lo)
{
  __shared__ float sm[8];
  int row = blockIdx.x, t = threadIdx.x;
  const float* x = rel + (size_t)row * 1024;
  float v[4]; float s = 0.f, ss = 0.f;
#pragma unroll
  for (int i=0;i<4;i++){ v[i] = x[t + 256*i]; s += v[i]; ss += v[i]*v[i]; }
  for (int o=32;o;o>>=1){ s += __shfl_xor(s,o); ss += __shfl_xor(ss,o); }
  int w = t >> 6;
  if ((t & 63) == 0){ sm[w] = s; sm[4+w] = ss; }
  __syncthreads();
  s  = sm[0]+sm[1]+sm[2]+sm[3];
  ss = sm[4]+sm[5]+sm[6]+sm[7];
  float mu  = s  * (1.0f/1024.0f);
  float var = ss * (1.0f/1024.0f) - mu*mu;
  float rs  = rsqrtf(var + 1e-5f);
#pragma unroll
  for (int i=0;i<4;i++){
    int cc = t + 256*i;
    float r = (v[i]-mu)*rs*g[cc] + b[cc];
    us h,l; split2(r,h,l);
    out_hi[(size_t)row*1024 + cc] = h;
    out_lo[(size_t)row*1024 + cc] = l;
  }
}

// ---------------- 4: log-bucket idx table (mirrors numpy f32 arithmetic) ----------------
__global__ void k_bucket(signed char* __restrict__ idxt)
{
  int i = blockIdx.x * 256 + threadIdx.x;
  if (i >= 2047) return;
  int d = i - 1023;
  int ad = d < 0 ? -d : d;
  int abspos = (d < 16 && d > -16) ? 15 : ad;
  int bucket;
  if (abspos <= 16) bucket = d;
  else {
    float num = (float)log((double)abspos * 0.0625);   // correctly-rounded f32 log
    float den = (float)log(7.9375);
    float lp = ceilf(num / den * 15.0f) + 16.0f;
    bucket = (int)lp * (d > 0 ? 1 : -1);
  }
  int s = bucket + 32;
  s = s < 0 ? 0 : (s > 63 ? 63 : s);
  idxt[i] = (signed char)s;
}

// ---------------- 5: split GEMM: C = (Ahi+Alo)(Bhi+Blo)^T + bias, 3 products ----------------
// MODE 0: out bf16 hi/lo [B,H,T,HD]; MODE 1: out bf16 hi/lo [B,H,HD,T]; MODE 2: fp32 [M][N]
template<int MODE>
__global__ __launch_bounds__(256) void k_gemm(const us* __restrict__ A_hi, const us* __restrict__ A_lo,
                                              const us* __restrict__ B_hi, const us* __restrict__ B_lo,
                                              const float* __restrict__ bias,
                                              us* __restrict__ out_hi, us* __restrict__ out_lo,
                                              float* __restrict__ out_f)
{
  __shared__ __align__(16) us a_lds[2][4096];
  __shared__ __align__(16) us b_lds[2][4096];
  int bid = blockIdx.x;
  int wg = (bid & 7) * 32 + (bid >> 3);        // XCD swizzle (256 % 8 == 0)
  int mt = wg >> 3, nt = wg & 7;
  int m0 = mt * 128, n0 = nt * 128;
  int t = threadIdx.x, w = t >> 6, lane = t & 63, lg = lane >> 4, li = lane & 15;
  int wm = w >> 1, wn = w & 1;
  f32x4 acc[4][4];
#pragma unroll
  for (int i=0;i<4;i++)
#pragma unroll
    for (int j=0;j<4;j++) acc[i][j] = fzero();

  auto stage = [&](int buf, int kt){
    int seg = kt >> 5, k0 = (kt & 31) * 32;
    const us* Ap = (seg == 2) ? A_lo : A_hi;
    const us* Bp = (seg == 1) ? B_lo : B_hi;
#pragma unroll
    for (int c = 0; c < 2; c++){
      int sbase = c*256 + w*64;
      int slot = sbase + lane;
      int g = slot ^ ((slot >> 3) & 7);
      int r = g >> 2, kc = g & 3;
      gload_lds16(Ap + (size_t)(m0 + r)*1024 + k0 + kc*8, (char*)&a_lds[buf][0] + sbase*16);
      gload_lds16(Bp + (size_t)(n0 + r)*1024 + k0 + kc*8, (char*)&b_lds[buf][0] + sbase*16);
    }
  };

  stage(0, 0);
  __syncthreads();
  int buf = 0;
  for (int kt = 0; kt < 96; kt++){
    if (kt + 1 < 96) stage(buf ^ 1, kt + 1);
    bf16x8 af[4], bfv[4];
#pragma unroll
    for (int mi=0;mi<4;mi++){
      int r = wm*64 + mi*16 + li;
      int s = (r*4 + lg); s ^= ((s >> 3) & 7);
      af[mi] = *(const bf16x8*)((char*)&a_lds[buf][0] + s*16);
    }
#pragma unroll
    for (int ni=0;ni<4;ni++){
      int r = wn*64 + ni*16 + li;
      int s = (r*4 + lg); s ^= ((s >> 3) & 7);
      bfv[ni] = *(const bf16x8*)((char*)&b_lds[buf][0] + s*16);
    }
#pragma unroll
    for (int mi=0;mi<4;mi++)
#pragma unroll
      for (int ni=0;ni<4;ni++)
        acc[mi][ni] = mfma16(af[mi], bfv[ni], acc[mi][ni]);
    __syncthreads();
    buf ^= 1;
  }

#pragma unroll
  for (int ni=0;ni<4;ni++){
    int n = n0 + wn*64 + ni*16 + li;
    float bn = bias[n];
    int hh = n >> 6, hd = n & 63;
#pragma unroll
    for (int mi=0;mi<4;mi++){
      int mb = m0 + wm*64 + mi*16 + lg*4;
#pragma unroll
      for (int j=0;j<4;j++){
        int m = mb + j;
        float val = acc[mi][ni][j] + bn;
        if (MODE == 2){
          out_f[(size_t)m*1024 + n] = val;
        } else {
          us h,l; split2(val,h,l);
          size_t idx;
          int bb = m >> 10, tp = m & 1023;
          if (MODE == 0) idx = (((size_t)(bb*16 + hh))*1024 + tp)*64 + hd;
          else           idx = (((size_t)(bb*16 + hh))*64 + hd)*1024 + tp;
          out_hi[idx] = h; out_lo[idx] = l;
        }
      }
    }
  }
}

// ---------------- 6: pos_k/pos_q = LN(rel) @ Wp + bp (3 products), out [H][2S][HD] hi/lo ----------------
__global__ __launch_bounds__(256) void k_pos(const us* __restrict__ reln_hi, const us* __restrict__ reln_lo,
                                             const us* __restrict__ wt,
                                             const float* __restrict__ bpk, const float* __restrict__ bpq,
                                             us* __restrict__ posk_hi, us* __restrict__ posk_lo,
                                             us* __restrict__ posq_hi, us* __restrict__ posq_lo)
{
  int ntile = blockIdx.x;            // 0..15
  int z = blockIdx.y;                // 0: pk (weight idx 3), 1: pq (weight idx 4)
  const us* W_hi = wt + (size_t)(3 + z) * 2097152;
  const us* W_lo = W_hi + 1048576;
  const float* bias = z ? bpq : bpk;
  us* out_hi = z ? posq_hi : posk_hi;
  us* out_lo = z ? posq_lo : posk_lo;
  int t = threadIdx.x, w = t >> 6, lane = t & 63, lg = lane >> 4, li = lane & 15;
  f32x4 acc[4];
#pragma unroll
  for (int i=0;i<4;i++) acc[i] = fzero();
  int srow = w*16 + li;
  for (int kt = 0; kt < 96; kt++){
    int seg = kt >> 5, k0 = (kt & 31)*32 + lg*8;
    const us* Ap = (seg == 2) ? reln_lo : reln_hi;
    const us* Bp = (seg == 1) ? W_lo : W_hi;
    bf16x8 a = *(const bf16x8*)(Ap + (size_t)srow*1024 + k0);
#pragma unroll
    for (int nf=0; nf<4; nf++){
      int n = ntile*64 + nf*16 + li;
      bf16x8 b = *(const bf16x8*)(Bp + (size_t)n*1024 + k0);
      acc[nf] = mfma16(a, b, acc[nf]);
    }
  }
#pragma unroll
  for (int nf=0;nf<4;nf++){
    int n = ntile*64 + nf*16 + li;
    float bn = bias[n];
    int h = n >> 6, hd = n & 63;
#pragma unroll
    for (int j=0;j<4;j++){
      int s = w*16 + lg*4 + j;
      us hh,ll; split2(acc[nf][j] + bn, hh, ll);
      out_hi[(size_t)h*4096 + s*64 + hd] = hh;
      out_lo[(size_t)h*4096 + s*64 + hd] = ll;
    }
  }
}

// ---------------- 7: c2p[b,h,q,s] / p2c[b,h,k,s] (3 products, bf16 out) ----------------
__global__ __launch_bounds__(256) void k_cp(const us* __restrict__ q_hi, const us* __restrict__ q_lo,
                                            const us* __restrict__ k_hi, const us* __restrict__ k_lo,
                                            const us* __restrict__ pk_hi, const us* __restrict__ pk_lo,
                                            const us* __restrict__ pq_hi, const us* __restrict__ pq_lo,
                                            us* __restrict__ c2p, us* __restrict__ p2c)
{
  int qt = blockIdx.x, bh = blockIdx.y, z = blockIdx.z;
  const us* X_hi = z ? k_hi : q_hi;
  const us* X_lo = z ? k_lo : q_lo;
  const us* P_hi = z ? pq_hi : pk_hi;
  const us* P_lo = z ? pq_lo : pk_lo;
  us* out = z ? p2c : c2p;
  int h = bh & 15;
  int t = threadIdx.x, w = t >> 6, lane = t & 63, lg = lane >> 4, li = lane & 15;
  f32x4 acc[4];
#pragma unroll
  for (int i=0;i<4;i++) acc[i] = fzero();
  size_t row = (size_t)bh*1024 + qt*64 + w*16 + li;
#pragma unroll
  for (int kk=0;kk<2;kk++){
    int k = kk*32 + lg*8;
    bf16x8 ah = *(const bf16x8*)(X_hi + row*64 + k);
    bf16x8 al = *(const bf16x8*)(X_lo + row*64 + k);
#pragma unroll
    for (int nf=0;nf<4;nf++){
      int s = nf*16 + li;
      bf16x8 bh_ = *(const bf16x8*)(P_hi + (size_t)h*4096 + s*64 + k);
      bf16x8 bl_ = *(const bf16x8*)(P_lo + (size_t)h*4096 + s*64 + k);
      acc[nf] = mfma16(ah, bh_, acc[nf]);
      acc[nf] = mfma16(ah, bl_, acc[nf]);
      acc[nf] = mfma16(al, bh_, acc[nf]);
    }
  }
  size_t obase = ((size_t)bh*1024 + qt*64 + w*16 + lg*4) * 64;
#pragma unroll
  for (int nf=0;nf<4;nf++)
#pragma unroll
    for (int j=0;j<4;j++)
      out[obase + (size_t)j*64 + nf*16 + li] = f2bf(acc[nf][j]);
}

// ---------------- 8: fused attention (split q/k/v, split P) ----------------
__global__ __launch_bounds__(256) void k_attn(const us* __restrict__ qhi, const us* __restrict__ qlo,
                                              const us* __restrict__ khi, const us* __restrict__ klo,
                                              const us* __restrict__ vhi, const us* __restrict__ vlo,
                                              const us* __restrict__ c2p, const us* __restrict__ p2c,
                                              const signed char* __restrict__ idxt,
                                              const unsigned char* __restrict__ mask,
                                              us* __restrict__ ctx_hi, us* __restrict__ ctx_lo)
{
  __shared__ __align__(16) us khi_lds[4096], klo_lds[4096], vhi_lds[4096], vlo_lds[4096];
  __shared__ __align__(16) us c2p_lds[4096], p2c_lds[4096];
  __shared__ __align__(16) us p_lds[4][1024];
  __shared__ signed char idx_lds[2048];

  const int qt = blockIdx.x, bh = blockIdx.y;
  const int b = bh >> 4, h = bh & 15;
  const int t = threadIdx.x, w = t >> 6, lane = t & 63, lg = lane >> 4, li = lane & 15;
  const int q0 = qt * 64;

  for (int i = t; i < 2047; i += 256) idx_lds[i] = idxt[i];
  {
    const us* src = c2p + ((size_t)bh*1024 + q0) * 64;
#pragma unroll
    for (int c = 0; c < 2; c++){
      int f = c*256 + t, r = f >> 3, kc = f & 7;
      *(ushort8*)&c2p_lds[r*64 + kc*8] = *(const ushort8*)(src + r*64 + kc*8);
    }
  }
  bf16x8 qfh[2], qfl[2];
  {
    const us* qph = qhi + ((size_t)bh*1024 + q0 + w*16 + li)*64 + lg*8;
    const us* qpl = qlo + ((size_t)bh*1024 + q0 + w*16 + li)*64 + lg*8;
    qfh[0] = *(const bf16x8*)(qph); qfh[1] = *(const bf16x8*)(qph + 32);
    qfl[0] = *(const bf16x8*)(qpl); qfl[1] = *(const bf16x8*)(qpl + 32);
  }
  float mrow[4], lrow[4];
  f32x4 accO[4];
#pragma unroll
  for (int j=0;j<4;j++){ mrow[j] = -INFINITY; lrow[j] = 0.f; }
#pragma unroll
  for (int nf=0;nf<4;nf++) accO[nf] = fzero();

  const float inv_scale = 0.07216878364870322f;  // 1/sqrt(64*3)
  const float inv_bias  = 0.08838834764831845f;  // 1/sqrt(64*2)
  const unsigned char* mptr = mask + b*1024;

  for (int kt = 0; kt < 16; kt++){
    const int k0 = kt * 64;
    __syncthreads();
    // stage K hi/lo, V hi/lo (each 64x64 bf16 = 512 chunks of 16B)
#pragma unroll
    for (int c = 0; c < 8; c++){
      int f = c*256 + t;
      int tile = f >> 9;
      int chunk = f & 511, r = chunk >> 3, kc = chunk & 7;
      const us* src; us* dst;
      if (tile == 0){ src = khi + ((size_t)bh*1024 + k0 + r)*64 + kc*8; dst = khi_lds; }
      else if (tile == 1){ src = klo + ((size_t)bh*1024 + k0 + r)*64 + kc*8; dst = klo_lds; }
      else if (tile == 2){ src = vhi + ((size_t)bh*64 + r)*1024 + k0 + kc*8; dst = vhi_lds; }
      else { src = vlo + ((size_t)bh*64 + r)*1024 + k0 + kc*8; dst = vlo_lds; }
      *(ushort8*)&dst[r*64 + ((kc ^ (r & 7))*8)] = *(const ushort8*)src;
    }
    {
      const us* src = p2c + ((size_t)bh*1024 + k0)*64;
#pragma unroll
      for (int c = 0; c < 2; c++){
        int f = c*256 + t, r = f >> 3, kc = f & 7;
        *(ushort8*)&p2c_lds[r*64 + kc*8] = *(const ushort8*)(src + r*64 + kc*8);
      }
    }
    __syncthreads();

    // QK^T: 3 products
    f32x4 sfr[4];
#pragma unroll
    for (int nf=0;nf<4;nf++) sfr[nf] = fzero();
#pragma unroll
    for (int kk=0; kk<2; kk++){
      int kc = kk*4 + lg;
#pragma unroll
      for (int nf=0; nf<4; nf++){
        int r = nf*16 + li;
        bf16x8 bh_ = *(const bf16x8*)&khi_lds[r*64 + ((kc ^ (r & 7))*8)];
        bf16x8 bl_ = *(const bf16x8*)&klo_lds[r*64 + ((kc ^ (r & 7))*8)];
        sfr[nf] = mfma16(qfh[kk], bh_, sfr[nf]);
        sfr[nf] = mfma16(qfh[kk], bl_, sfr[nf]);
        sfr[nf] = mfma16(qfl[kk], bh_, sfr[nf]);
      }
    }
    // scale + rel-pos bias + mask
    float sv[4][4], cand[4];
#pragma unroll
    for (int j=0;j<4;j++) cand[j] = -INFINITY;
#pragma unroll
    for (int nf=0; nf<4; nf++){
      int kloc = nf*16 + li;
      bool mk = mptr[k0 + kloc] != 0;
#pragma unroll
      for (int j=0;j<4;j++){
        int qloc = w*16 + lg*4 + j;
        int d = (q0 + qloc) - (k0 + kloc);
        int idx = (int)idx_lds[d + 1023];
        float s = sfr[nf][j]*inv_scale
                + (b2f(c2p_lds[qloc*64 + idx]) + b2f(p2c_lds[kloc*64 + idx]))*inv_bias;
        if (mk) s = -INFINITY;
        sv[nf][j] = s;
        cand[j] = fmaxf(cand[j], s);
      }
    }
    for (int o=1;o<16;o<<=1)
#pragma unroll
      for (int j=0;j<4;j++)
        cand[j] = fmaxf(cand[j], __shfl_xor(cand[j], o));
    float corr[4];
#pragma unroll
    for (int j=0;j<4;j++){
      float nm = fmaxf(mrow[j], cand[j]);
      corr[j] = __expf(mrow[j] - nm);
      mrow[j] = nm;
      lrow[j] *= corr[j];
    }
    us* pl = &p_lds[w][0];
    // write P_hi; keep p in sv
#pragma unroll
    for (int nf=0; nf<4; nf++){
      int col = nf*16 + li;
#pragma unroll
      for (int j=0;j<4;j++){
        float p = __expf(sv[nf][j] - mrow[j]);
        lrow[j] += p;
        sv[nf][j] = p;
        int row = lg*4 + j;
        pl[row*64 + ((col & 7) | ((((col >> 3) ^ (row & 7))) << 3))] = f2bf(p);
      }
      f32x4 a = accO[nf];
      a.x *= corr[0]; a.y *= corr[1]; a.z *= corr[2]; a.w *= corr[3];
      accO[nf] = a;
    }
    // PV phase 1: Phi*Vhi + Phi*Vlo   (p_lds wave-private; same-wave DS ordering)
#pragma unroll
    for (int kk=0;kk<2;kk++){
      int kc = kk*4 + lg;
      bf16x8 af = *(const bf16x8*)((char*)pl + li*128 + ((kc ^ (li & 7)) * 16));
#pragma unroll
      for (int nf=0;nf<4;nf++){
        int r = nf*16 + li;
        bf16x8 bh_ = *(const bf16x8*)&vhi_lds[r*64 + ((kc ^ (r & 7))*8)];
        bf16x8 bl_ = *(const bf16x8*)&vlo_lds[r*64 + ((kc ^ (r & 7))*8)];
        accO[nf] = mfma16(af, bh_, accO[nf]);
        accO[nf] = mfma16(af, bl_, accO[nf]);
      }
    }
    // write P_lo (after phase-1 reads, program order)
#pragma unroll
    for (int nf=0; nf<4; nf++){
      int col = nf*16 + li;
#pragma unroll
      for (int j=0;j<4;j++){
        float p = sv[nf][j];
        us ph = f2bf(p);
        float plo = p - b2f(ph);
        int row = lg*4 + j;
        pl[row*64 + ((col & 7) | ((((col >> 3) ^ (row & 7))) << 3))] = f2bf(plo);
      }
    }
    // PV phase 2: Plo*Vhi
#pragma unroll
    for (int kk=0;kk<2;kk++){
      int kc = kk*4 + lg;
      bf16x8 af = *(const bf16x8*)((char*)pl + li*128 + ((kc ^ (li & 7)) * 16));
#pragma unroll
      for (int nf=0;nf<4;nf++){
        int r = nf*16 + li;
        bf16x8 bh_ = *(const bf16x8*)&vhi_lds[r*64 + ((kc ^ (r & 7))*8)];
        accO[nf] = mfma16(af, bh_, accO[nf]);
      }
    }
  }

  for (int o=1;o<16;o<<=1)
#pragma unroll
    for (int j=0;j<4;j++)
      lrow[j] += __shfl_xor(lrow[j], o);
#pragma unroll
  for (int nf=0;nf<4;nf++)
#pragma unroll
    for (int j=0;j<4;j++){
      int qloc = w*16 + lg*4 + j;
      float o = accO[nf][j] / lrow[j];
      size_t idx = ((size_t)(b*1024 + q0 + qloc))*1024 + h*64 + nf*16 + li;
      us hh,ll; split2(o,hh,ll);
      ctx_hi[idx] = hh; ctx_lo[idx] = ll;
    }
}

// ---------------- launch ----------------
extern "C" void kernel_launch(void* const* d_in, const int* in_sizes, int n_in,
                              void* d_out, int out_size, void* d_ws, size_t ws_size,
                              hipStream_t stream)
{
  (void)in_sizes; (void)n_in; (void)out_size; (void)ws_size;
  const float* query = (const float*)d_in[0];
  const float* kvst  = (const float*)d_in[1];
  const unsigned char* mask = (const unsigned char*)d_in[2];
  const float* Wq = (const float*)d_in[3];  const float* bq = (const float*)d_in[4];
  const float* Wk = (const float*)d_in[5];  const float* bk = (const float*)d_in[6];
  const float* Wv = (const float*)d_in[7];  const float* bv = (const float*)d_in[8];
  const float* Wo = (const float*)d_in[9];  const float* bo = (const float*)d_in[10];
  const float* rel = (const float*)d_in[11];
  const float* lng = (const float*)d_in[12]; const float* lnb = (const float*)d_in[13];
  const float* Wpk = (const float*)d_in[14]; const float* bpk = (const float*)d_in[15];
  const float* Wpq = (const float*)d_in[16]; const float* bpq = (const float*)d_in[17];

  char* ws = (char*)d_ws;
  const size_t MB = 1024*1024;
  // [0..16)  Xq hi/lo, later vtb hi/lo
  us* Xq_hi  = (us*)(ws + 0);      us* Xq_lo  = (us*)(ws + 8*MB);
  us* vtb_hi = (us*)(ws + 0);      us* vtb_lo = (us*)(ws + 8*MB);
  // [16..32) Xkv hi/lo, later c2p/p2c (bf16)
  us* Xkv_hi = (us*)(ws + 16*MB);  us* Xkv_lo = (us*)(ws + 24*MB);
  us* c2p    = (us*)(ws + 16*MB);  us* p2c    = (us*)(ws + 24*MB);
  // [32..56) weights (z*4MB: hi, lo): 0 Wq, 1 Wk, 2 Wv, 3 Wpk, 4 Wpq, 5 Wo
  us* Wt = (us*)(ws + 32*MB);
  // [32..48) reused for ctx hi/lo after k_pos + QKV GEMMs are done
  us* ctx_hi = (us*)(ws + 32*MB);  us* ctx_lo = (us*)(ws + 40*MB);
  // [56..57) small
  us* reln_hi = (us*)(ws + 56*MB);
  us* reln_lo = (us*)(ws + 56*MB + 128*1024);
  us* posk_hi = (us*)(ws + 56*MB + 256*1024);
  us* posk_lo = (us*)(ws + 56*MB + 384*1024);
  us* posq_hi = (us*)(ws + 56*MB + 512*1024);
  us* posq_lo = (us*)(ws + 56*MB + 640*1024);
  signed char* idxt = (signed char*)(ws + 56*MB + 768*1024);
  // [57..89) q/k buffers hi/lo
  us* qbuf_hi = (us*)(ws + 57*MB); us* qbuf_lo = (us*)(ws + 65*MB);
  us* kbuf_hi = (us*)(ws + 73*MB); us* kbuf_lo = (us*)(ws + 81*MB);

  k_convx<<<8192, 256, 0, stream>>>(query, kvst, Xq_hi, Xq_lo, Xkv_hi, Xkv_lo);
  k_convw<<<dim3(32,32,6), 256, 0, stream>>>(Wq, Wk, Wv, Wpk, Wpq, Wo, Wt);
  k_lnrel<<<64, 256, 0, stream>>>(rel, lng, lnb, reln_hi, reln_lo);
  k_bucket<<<8, 256, 0, stream>>>(idxt);

  // q GEMM first (Xq region is reused by v GEMM's output)
  k_gemm<0><<<256, 256, 0, stream>>>(Xq_hi,  Xq_lo,  Wt + 0*2097152, Wt + 0*2097152 + 1048576, bq, qbuf_hi, qbuf_lo, nullptr);
  k_gemm<0><<<256, 256, 0, stream>>>(Xkv_hi, Xkv_lo, Wt + 1*2097152, Wt + 1*2097152 + 1048576, bk, kbuf_hi, kbuf_lo, nullptr);
  k_gemm<1><<<256, 256, 0, stream>>>(Xkv_hi, Xkv_lo, Wt + 2*2097152, Wt + 2*2097152 + 1048576, bv, vtb_hi, vtb_lo, nullptr);

  k_pos<<<dim3(16,2), 256, 0, stream>>>(reln_hi, reln_lo, Wt, bpk, bpq, posk_hi, posk_lo, posq_hi, posq_lo);
  k_cp<<<dim3(16,64,2), 256, 0, stream>>>(qbuf_hi, qbuf_lo, kbuf_hi, kbuf_lo,
                                          posk_hi, posk_lo, posq_hi, posq_lo, c2p, p2c);

  k_attn<<<dim3(16,64), 256, 0, stream>>>(qbuf_hi, qbuf_lo, kbuf_hi, kbuf_lo, vtb_hi, vtb_lo,
                                          c2p, p2c, idxt, mask, ctx_hi, ctx_lo);

  k_gemm<2><<<256, 256, 0, stream>>>(ctx_hi, ctx_lo, Wt + 5*2097152, Wt + 5*2097152 + 1048576, bo, nullptr, nullptr, (float*)d_out);
}

// Round 3
// 420.362 us; speedup vs baseline: 1.1863x; 1.1863x over previous
//
#include <hip/hip_runtime.h>
#include <cstdint>
#include <math.h>

typedef unsigned short us;
typedef __attribute__((ext_vector_type(8))) __bf16 bf16x8;
typedef __attribute__((ext_vector_type(8))) unsigned short ushort8;
typedef __attribute__((ext_vector_type(4))) float f32x4;

__device__ __forceinline__ us f2bf(float x){
  union { float f; unsigned int u; } v; v.f = x;
  unsigned int r = v.u + 0x7FFFu + ((v.u >> 16) & 1u);   // RNE
  return (us)(r >> 16);
}
__device__ __forceinline__ float b2f(us u){
  union { unsigned int u; float f; } v; v.u = ((unsigned int)u) << 16; return v.f;
}
__device__ __forceinline__ void split2(float x, us& hi, us& lo){
  hi = f2bf(x); lo = f2bf(x - b2f(hi));
}
__device__ __forceinline__ f32x4 fzero(){ f32x4 v; v.x=0.f; v.y=0.f; v.z=0.f; v.w=0.f; return v; }
__device__ __forceinline__ f32x4 mfma16(bf16x8 a, bf16x8 b, f32x4 c){
  return __builtin_amdgcn_mfma_f32_16x16x32_bf16(a, b, c, 0, 0, 0);
}
__device__ __forceinline__ void gload_lds16(const void* g, void* l){
  __builtin_amdgcn_global_load_lds(
      (const __attribute__((address_space(1))) unsigned int*)(uintptr_t)g,
      (__attribute__((address_space(3))) unsigned int*)(uintptr_t)l,
      16, 0, 0);
}

// ---------------- 1: fp32 -> bf16 hi/lo split of inputs ----------------
__global__ __launch_bounds__(256) void k_convx(const float* __restrict__ xq,
                                               const float* __restrict__ xkv,
                                               us* __restrict__ qhi, us* __restrict__ qlo,
                                               us* __restrict__ kvhi, us* __restrict__ kvlo)
{
  int i = blockIdx.x * 256 + threadIdx.x;   // float4 units, 2M total
  const float* src; us *dh, *dl;
  if (i < 1048576) { src = xq  + (size_t)i*4;            dh = qhi  + (size_t)i*4;            dl = qlo  + (size_t)i*4; }
  else             { src = xkv + (size_t)(i-1048576)*4;  dh = kvhi + (size_t)(i-1048576)*4;  dl = kvlo + (size_t)(i-1048576)*4; }
  f32x4 v = *(const f32x4*)src;
  us h0,l0,h1,l1,h2,l2,h3,l3;
  split2(v.x,h0,l0); split2(v.y,h1,l1); split2(v.z,h2,l2); split2(v.w,h3,l3);
  dh[0]=h0; dh[1]=h1; dh[2]=h2; dh[3]=h3;
  dl[0]=l0; dl[1]=l1; dl[2]=l2; dl[3]=l3;
}

// ---------------- 2: weight transpose + hi/lo split: Wt[n][k] ----------------
__global__ __launch_bounds__(256) void k_convw(const float* w0, const float* w1, const float* w2,
                                               const float* w3, const float* w4, const float* w5,
                                               us* __restrict__ wt)
{
  __shared__ float tile[32][33];
  int z = blockIdx.z;
  const float* W = (z==0)?w0:(z==1)?w1:(z==2)?w2:(z==3)?w3:(z==4)?w4:w5;
  us* dst_hi = wt + (size_t)z * 2097152;
  us* dst_lo = dst_hi + 1048576;
  int n0 = blockIdx.x * 32, k0 = blockIdx.y * 32;
  int c = threadIdx.x & 31, r = threadIdx.x >> 5;
#pragma unroll
  for (int i = 0; i < 4; i++)
    tile[r + i*8][c] = W[(size_t)(k0 + r + i*8)*1024 + n0 + c];
  __syncthreads();
#pragma unroll
  for (int i = 0; i < 4; i++){
    int nn = r + i*8;
    us h,l; split2(tile[c][nn], h, l);
    dst_hi[(size_t)(n0 + nn)*1024 + k0 + c] = h;
    dst_lo[(size_t)(n0 + nn)*1024 + k0 + c] = l;
  }
}

// ---------------- 3: layernorm(rel_emb) -> bf16 hi/lo ----------------
__global__ __launch_bounds__(256) void k_lnrel(const float* __restrict__ rel,
                                               const float* __restrict__ g,
                                               const float* __restrict__ b,
                                               us* __restrict__ out_hi,
                                               us* __restrict__ out_lo)
{
  __shared__ float sm[8];
  int row = blockIdx.x, t = threadIdx.x;
  const float* x = rel + (size_t)row * 1024;
  float v[4]; float s = 0.f, ss = 0.f;
#pragma unroll
  for (int i=0;i<4;i++){ v[i] = x[t + 256*i]; s += v[i]; ss += v[i]*v[i]; }
  for (int o=32;o;o>>=1){ s += __shfl_xor(s,o); ss += __shfl_xor(ss,o); }
  int w = t >> 6;
  if ((t & 63) == 0){ sm[w] = s; sm[4+w] = ss; }
  __syncthreads();
  s  = sm[0]+sm[1]+sm[2]+sm[3];
  ss = sm[4]+sm[5]+sm[6]+sm[7];
  float mu  = s  * (1.0f/1024.0f);
  float var = ss * (1.0f/1024.0f) - mu*mu;
  float rs  = rsqrtf(var + 1e-5f);
#pragma unroll
  for (int i=0;i<4;i++){
    int cc = t + 256*i;
    float r = (v[i]-mu)*rs*g[cc] + b[cc];
    us h,l; split2(r,h,l);
    out_hi[(size_t)row*1024 + cc] = h;
    out_lo[(size_t)row*1024 + cc] = l;
  }
}

// ---------------- 4: log-bucket idx table (mirrors numpy f32 arithmetic) ----------------
__global__ void k_bucket(signed char* __restrict__ idxt)
{
  int i = blockIdx.x * 256 + threadIdx.x;
  if (i >= 2047) return;
  int d = i - 1023;
  int ad = d < 0 ? -d : d;
  int abspos = (d < 16 && d > -16) ? 15 : ad;
  int bucket;
  if (abspos <= 16) bucket = d;
  else {
    float num = (float)log((double)abspos * 0.0625);   // correctly-rounded f32 log
    float den = (float)log(7.9375);
    float lp = ceilf(num / den * 15.0f) + 16.0f;
    bucket = (int)lp * (d > 0 ? 1 : -1);
  }
  int s = bucket + 32;
  s = s < 0 ? 0 : (s > 63 ? 63 : s);
  idxt[i] = (signed char)s;
}

// ---------------- 5: split GEMM: C = (Ahi+Alo)(Bhi+Blo)^T + bias, 3 products ----------------
// MODE 0: out bf16 hi/lo [B,H,T,HD]; MODE 1: out bf16 hi/lo [B,H,HD,T]; MODE 2: fp32 [M][N]
template<int MODE>
__global__ __launch_bounds__(256) void k_gemm(const us* __restrict__ A_hi, const us* __restrict__ A_lo,
                                              const us* __restrict__ B_hi, const us* __restrict__ B_lo,
                                              const float* __restrict__ bias,
                                              us* __restrict__ out_hi, us* __restrict__ out_lo,
                                              float* __restrict__ out_f)
{
  __shared__ __align__(16) us a_lds[2][4096];
  __shared__ __align__(16) us b_lds[2][4096];
  int bid = blockIdx.x;
  int wg = (bid & 7) * 32 + (bid >> 3);        // XCD swizzle (256 % 8 == 0)
  int mt = wg >> 3, nt = wg & 7;
  int m0 = mt * 128, n0 = nt * 128;
  int t = threadIdx.x, w = t >> 6, lane = t & 63, lg = lane >> 4, li = lane & 15;
  int wm = w >> 1, wn = w & 1;
  f32x4 acc[4][4];
#pragma unroll
  for (int i=0;i<4;i++)
#pragma unroll
    for (int j=0;j<4;j++) acc[i][j] = fzero();

  auto stage = [&](int buf, int kt){
    int seg = kt >> 5, k0 = (kt & 31) * 32;
    const us* Ap = (seg == 2) ? A_lo : A_hi;
    const us* Bp = (seg == 1) ? B_lo : B_hi;
#pragma unroll
    for (int c = 0; c < 2; c++){
      int sbase = c*256 + w*64;
      int slot = sbase + lane;
      int g = slot ^ ((slot >> 3) & 7);
      int r = g >> 2, kc = g & 3;
      gload_lds16(Ap + (size_t)(m0 + r)*1024 + k0 + kc*8, (char*)&a_lds[buf][0] + sbase*16);
      gload_lds16(Bp + (size_t)(n0 + r)*1024 + k0 + kc*8, (char*)&b_lds[buf][0] + sbase*16);
    }
  };

  stage(0, 0);
  __syncthreads();
  int buf = 0;
  for (int kt = 0; kt < 96; kt++){
    if (kt + 1 < 96) stage(buf ^ 1, kt + 1);
    bf16x8 af[4], bfv[4];
#pragma unroll
    for (int mi=0;mi<4;mi++){
      int r = wm*64 + mi*16 + li;
      int s = (r*4 + lg); s ^= ((s >> 3) & 7);
      af[mi] = *(const bf16x8*)((char*)&a_lds[buf][0] + s*16);
    }
#pragma unroll
    for (int ni=0;ni<4;ni++){
      int r = wn*64 + ni*16 + li;
      int s = (r*4 + lg); s ^= ((s >> 3) & 7);
      bfv[ni] = *(const bf16x8*)((char*)&b_lds[buf][0] + s*16);
    }
#pragma unroll
    for (int mi=0;mi<4;mi++)
#pragma unroll
      for (int ni=0;ni<4;ni++)
        acc[mi][ni] = mfma16(af[mi], bfv[ni], acc[mi][ni]);
    __syncthreads();
    buf ^= 1;
  }

#pragma unroll
  for (int ni=0;ni<4;ni++){
    int n = n0 + wn*64 + ni*16 + li;
    float bn = bias[n];
    int hh = n >> 6, hd = n & 63;
#pragma unroll
    for (int mi=0;mi<4;mi++){
      int mb = m0 + wm*64 + mi*16 + lg*4;
#pragma unroll
      for (int j=0;j<4;j++){
        int m = mb + j;
        float val = acc[mi][ni][j] + bn;
        if (MODE == 2){
          out_f[(size_t)m*1024 + n] = val;
        } else {
          us h,l; split2(val,h,l);
          size_t idx;
          int bb = m >> 10, tp = m & 1023;
          if (MODE == 0) idx = (((size_t)(bb*16 + hh))*1024 + tp)*64 + hd;
          else           idx = (((size_t)(bb*16 + hh))*64 + hd)*1024 + tp;
          out_hi[idx] = h; out_lo[idx] = l;
        }
      }
    }
  }
}

// ---------------- 6: pos_k/pos_q = LN(rel) @ Wp + bp (3 products), out [H][2S][HD] hi/lo ----------------
__global__ __launch_bounds__(256) void k_pos(const us* __restrict__ reln_hi, const us* __restrict__ reln_lo,
                                             const us* __restrict__ wt,
                                             const float* __restrict__ bpk, const float* __restrict__ bpq,
                                             us* __restrict__ posk_hi, us* __restrict__ posk_lo,
                                             us* __restrict__ posq_hi, us* __restrict__ posq_lo)
{
  int ntile = blockIdx.x;            // 0..15
  int z = blockIdx.y;                // 0: pk (weight idx 3), 1: pq (weight idx 4)
  const us* W_hi = wt + (size_t)(3 + z) * 2097152;
  const us* W_lo = W_hi + 1048576;
  const float* bias = z ? bpq : bpk;
  us* out_hi = z ? posq_hi : posk_hi;
  us* out_lo = z ? posq_lo : posk_lo;
  int t = threadIdx.x, w = t >> 6, lane = t & 63, lg = lane >> 4, li = lane & 15;
  f32x4 acc[4];
#pragma unroll
  for (int i=0;i<4;i++) acc[i] = fzero();
  int srow = w*16 + li;
  for (int kt = 0; kt < 96; kt++){
    int seg = kt >> 5, k0 = (kt & 31)*32 + lg*8;
    const us* Ap = (seg == 2) ? reln_lo : reln_hi;
    const us* Bp = (seg == 1) ? W_lo : W_hi;
    bf16x8 a = *(const bf16x8*)(Ap + (size_t)srow*1024 + k0);
#pragma unroll
    for (int nf=0; nf<4; nf++){
      int n = ntile*64 + nf*16 + li;
      bf16x8 b = *(const bf16x8*)(Bp + (size_t)n*1024 + k0);
      acc[nf] = mfma16(a, b, acc[nf]);
    }
  }
#pragma unroll
  for (int nf=0;nf<4;nf++){
    int n = ntile*64 + nf*16 + li;
    float bn = bias[n];
    int h = n >> 6, hd = n & 63;
#pragma unroll
    for (int j=0;j<4;j++){
      int s = w*16 + lg*4 + j;
      us hh,ll; split2(acc[nf][j] + bn, hh, ll);
      out_hi[(size_t)h*4096 + s*64 + hd] = hh;
      out_lo[(size_t)h*4096 + s*64 + hd] = ll;
    }
  }
}

// ---------------- 7: c2p[b,h,q,s] / p2c[b,h,k,s] (3 products, bf16 out) ----------------
__global__ __launch_bounds__(256) void k_cp(const us* __restrict__ q_hi, const us* __restrict__ q_lo,
                                            const us* __restrict__ k_hi, const us* __restrict__ k_lo,
                                            const us* __restrict__ pk_hi, const us* __restrict__ pk_lo,
                                            const us* __restrict__ pq_hi, const us* __restrict__ pq_lo,
                                            us* __restrict__ c2p, us* __restrict__ p2c)
{
  int qt = blockIdx.x, bh = blockIdx.y, z = blockIdx.z;
  const us* X_hi = z ? k_hi : q_hi;
  const us* X_lo = z ? k_lo : q_lo;
  const us* P_hi = z ? pq_hi : pk_hi;
  const us* P_lo = z ? pq_lo : pk_lo;
  us* out = z ? p2c : c2p;
  int h = bh & 15;
  int t = threadIdx.x, w = t >> 6, lane = t & 63, lg = lane >> 4, li = lane & 15;
  f32x4 acc[4];
#pragma unroll
  for (int i=0;i<4;i++) acc[i] = fzero();
  size_t row = (size_t)bh*1024 + qt*64 + w*16 + li;
#pragma unroll
  for (int kk=0;kk<2;kk++){
    int k = kk*32 + lg*8;
    bf16x8 ah = *(const bf16x8*)(X_hi + row*64 + k);
    bf16x8 al = *(const bf16x8*)(X_lo + row*64 + k);
#pragma unroll
    for (int nf=0;nf<4;nf++){
      int s = nf*16 + li;
      bf16x8 bh_ = *(const bf16x8*)(P_hi + (size_t)h*4096 + s*64 + k);
      bf16x8 bl_ = *(const bf16x8*)(P_lo + (size_t)h*4096 + s*64 + k);
      acc[nf] = mfma16(ah, bh_, acc[nf]);
      acc[nf] = mfma16(ah, bl_, acc[nf]);
      acc[nf] = mfma16(al, bh_, acc[nf]);
    }
  }
  size_t obase = ((size_t)bh*1024 + qt*64 + w*16 + lg*4) * 64;
#pragma unroll
  for (int nf=0;nf<4;nf++)
#pragma unroll
    for (int j=0;j<4;j++)
      out[obase + (size_t)j*64 + nf*16 + li] = f2bf(acc[nf][j]);
}

// ---------------- 8: fused attention (single-product QK/PV, padded bias tiles) ----------------
__global__ __launch_bounds__(256) void k_attn(const us* __restrict__ qhi,
                                              const us* __restrict__ khi,
                                              const us* __restrict__ vhi,
                                              const us* __restrict__ c2p, const us* __restrict__ p2c,
                                              const signed char* __restrict__ idxt,
                                              const unsigned char* __restrict__ mask,
                                              us* __restrict__ ctx_hi, us* __restrict__ ctx_lo)
{
  __shared__ __align__(16) us khi_lds[4096], vhi_lds[4096];
  __shared__ __align__(16) us c2p_lds[64*72], p2c_lds[64*72];   // padded: 144B row stride
  __shared__ __align__(16) us p_lds[4][1024];
  __shared__ signed char idx_lds[2048];

  const int qt = blockIdx.x, bh = blockIdx.y;
  const int b = bh >> 4, h = bh & 15;
  const int t = threadIdx.x, w = t >> 6, lane = t & 63, lg = lane >> 4, li = lane & 15;
  const int q0 = qt * 64;

  for (int i = t; i < 2047; i += 256) idx_lds[i] = idxt[i];
  {
    const us* src = c2p + ((size_t)bh*1024 + q0) * 64;
#pragma unroll
    for (int c = 0; c < 2; c++){
      int f = c*256 + t, r = f >> 3, kc = f & 7;
      *(ushort8*)&c2p_lds[r*72 + kc*8] = *(const ushort8*)(src + r*64 + kc*8);
    }
  }
  bf16x8 qfh[2];
  {
    const us* qph = qhi + ((size_t)bh*1024 + q0 + w*16 + li)*64 + lg*8;
    qfh[0] = *(const bf16x8*)(qph); qfh[1] = *(const bf16x8*)(qph + 32);
  }
  float mrow[4], lrow[4];
  f32x4 accO[4];
#pragma unroll
  for (int j=0;j<4;j++){ mrow[j] = -INFINITY; lrow[j] = 0.f; }
#pragma unroll
  for (int nf=0;nf<4;nf++) accO[nf] = fzero();

  const float inv_scale = 0.07216878364870322f;  // 1/sqrt(64*3)
  const float inv_bias  = 0.08838834764831845f;  // 1/sqrt(64*2)
  const unsigned char* mptr = mask + b*1024;

  for (int kt = 0; kt < 16; kt++){
    const int k0 = kt * 64;
    __syncthreads();
    // stage K hi, V hi (each 64x64 bf16 = 512 chunks of 16B), swizzled
#pragma unroll
    for (int c = 0; c < 4; c++){
      int f = c*256 + t;
      int tile = f >> 9;
      int chunk = f & 511, r = chunk >> 3, kc = chunk & 7;
      const us* src; us* dst;
      if (tile == 0){ src = khi + ((size_t)bh*1024 + k0 + r)*64 + kc*8; dst = khi_lds; }
      else          { src = vhi + ((size_t)bh*64 + r)*1024 + k0 + kc*8; dst = vhi_lds; }
      *(ushort8*)&dst[r*64 + ((kc ^ (r & 7))*8)] = *(const ushort8*)src;
    }
    {
      const us* src = p2c + ((size_t)bh*1024 + k0)*64;
#pragma unroll
      for (int c = 0; c < 2; c++){
        int f = c*256 + t, r = f >> 3, kc = f & 7;
        *(ushort8*)&p2c_lds[r*72 + kc*8] = *(const ushort8*)(src + r*64 + kc*8);
      }
    }
    __syncthreads();

    // QK^T single product
    f32x4 sfr[4];
#pragma unroll
    for (int nf=0;nf<4;nf++) sfr[nf] = fzero();
#pragma unroll
    for (int kk=0; kk<2; kk++){
      int kc = kk*4 + lg;
#pragma unroll
      for (int nf=0; nf<4; nf++){
        int r = nf*16 + li;
        bf16x8 bh_ = *(const bf16x8*)&khi_lds[r*64 + ((kc ^ (r & 7))*8)];
        sfr[nf] = mfma16(qfh[kk], bh_, sfr[nf]);
      }
    }
    // scale + rel-pos bias + mask
    float sv[4][4], cand[4];
#pragma unroll
    for (int j=0;j<4;j++) cand[j] = -INFINITY;
#pragma unroll
    for (int nf=0; nf<4; nf++){
      int kloc = nf*16 + li;
      bool mk = mptr[k0 + kloc] != 0;
#pragma unroll
      for (int j=0;j<4;j++){
        int qloc = w*16 + lg*4 + j;
        int d = (q0 + qloc) - (k0 + kloc);
        int idx = (int)idx_lds[d + 1023];
        float s = sfr[nf][j]*inv_scale
                + (b2f(c2p_lds[qloc*72 + idx]) + b2f(p2c_lds[kloc*72 + idx]))*inv_bias;
        if (mk) s = -INFINITY;
        sv[nf][j] = s;
        cand[j] = fmaxf(cand[j], s);
      }
    }
    for (int o=1;o<16;o<<=1)
#pragma unroll
      for (int j=0;j<4;j++)
        cand[j] = fmaxf(cand[j], __shfl_xor(cand[j], o));
    float corr[4];
#pragma unroll
    for (int j=0;j<4;j++){
      float nm = fmaxf(mrow[j], cand[j]);
      corr[j] = __expf(mrow[j] - nm);
      mrow[j] = nm;
      lrow[j] *= corr[j];
    }
    us* pl = &p_lds[w][0];
#pragma unroll
    for (int nf=0; nf<4; nf++){
      int col = nf*16 + li;
#pragma unroll
      for (int j=0;j<4;j++){
        float p = __expf(sv[nf][j] - mrow[j]);
        lrow[j] += p;
        int row = lg*4 + j;
        pl[row*64 + ((col & 7) | ((((col >> 3) ^ (row & 7))) << 3))] = f2bf(p);
      }
      f32x4 a = accO[nf];
      a.x *= corr[0]; a.y *= corr[1]; a.z *= corr[2]; a.w *= corr[3];
      accO[nf] = a;
    }
    // PV single product (p_lds wave-private; same-wave DS ordering)
#pragma unroll
    for (int kk=0;kk<2;kk++){
      int kc = kk*4 + lg;
      bf16x8 af = *(const bf16x8*)((char*)pl + li*128 + ((kc ^ (li & 7)) * 16));
#pragma unroll
      for (int nf=0;nf<4;nf++){
        int r = nf*16 + li;
        bf16x8 bh_ = *(const bf16x8*)&vhi_lds[r*64 + ((kc ^ (r & 7))*8)];
        accO[nf] = mfma16(af, bh_, accO[nf]);
      }
    }
  }

  for (int o=1;o<16;o<<=1)
#pragma unroll
    for (int j=0;j<4;j++)
      lrow[j] += __shfl_xor(lrow[j], o);
#pragma unroll
  for (int nf=0;nf<4;nf++)
#pragma unroll
    for (int j=0;j<4;j++){
      int qloc = w*16 + lg*4 + j;
      float o = accO[nf][j] / lrow[j];
      size_t idx = ((size_t)(b*1024 + q0 + qloc))*1024 + h*64 + nf*16 + li;
      us hh,ll; split2(o,hh,ll);
      ctx_hi[idx] = hh; ctx_lo[idx] = ll;
    }
}

// ---------------- launch ----------------
extern "C" void kernel_launch(void* const* d_in, const int* in_sizes, int n_in,
                              void* d_out, int out_size, void* d_ws, size_t ws_size,
                              hipStream_t stream)
{
  (void)in_sizes; (void)n_in; (void)out_size; (void)ws_size;
  const float* query = (const float*)d_in[0];
  const float* kvst  = (const float*)d_in[1];
  const unsigned char* mask = (const unsigned char*)d_in[2];
  const float* Wq = (const float*)d_in[3];  const float* bq = (const float*)d_in[4];
  const float* Wk = (const float*)d_in[5];  const float* bk = (const float*)d_in[6];
  const float* Wv = (const float*)d_in[7];  const float* bv = (const float*)d_in[8];
  const float* Wo = (const float*)d_in[9];  const float* bo = (const float*)d_in[10];
  const float* rel = (const float*)d_in[11];
  const float* lng = (const float*)d_in[12]; const float* lnb = (const float*)d_in[13];
  const float* Wpk = (const float*)d_in[14]; const float* bpk = (const float*)d_in[15];
  const float* Wpq = (const float*)d_in[16]; const float* bpq = (const float*)d_in[17];

  char* ws = (char*)d_ws;
  const size_t MB = 1024*1024;
  // [0..16)  Xq hi/lo, later vtb hi/lo
  us* Xq_hi  = (us*)(ws + 0);      us* Xq_lo  = (us*)(ws + 8*MB);
  us* vtb_hi = (us*)(ws + 0);      us* vtb_lo = (us*)(ws + 8*MB);
  // [16..32) Xkv hi/lo, later c2p/p2c (bf16)
  us* Xkv_hi = (us*)(ws + 16*MB);  us* Xkv_lo = (us*)(ws + 24*MB);
  us* c2p    = (us*)(ws + 16*MB);  us* p2c    = (us*)(ws + 24*MB);
  // [32..56) weights (z*4MB: hi, lo): 0 Wq, 1 Wk, 2 Wv, 3 Wpk, 4 Wpq, 5 Wo
  us* Wt = (us*)(ws + 32*MB);
  // [32..48) reused for ctx hi/lo after k_pos + QKV GEMMs are done
  us* ctx_hi = (us*)(ws + 32*MB);  us* ctx_lo = (us*)(ws + 40*MB);
  // [56..57) small
  us* reln_hi = (us*)(ws + 56*MB);
  us* reln_lo = (us*)(ws + 56*MB + 128*1024);
  us* posk_hi = (us*)(ws + 56*MB + 256*1024);
  us* posk_lo = (us*)(ws + 56*MB + 384*1024);
  us* posq_hi = (us*)(ws + 56*MB + 512*1024);
  us* posq_lo = (us*)(ws + 56*MB + 640*1024);
  signed char* idxt = (signed char*)(ws + 56*MB + 768*1024);
  // [57..89) q/k buffers hi/lo
  us* qbuf_hi = (us*)(ws + 57*MB); us* qbuf_lo = (us*)(ws + 65*MB);
  us* kbuf_hi = (us*)(ws + 73*MB); us* kbuf_lo = (us*)(ws + 81*MB);

  k_convx<<<8192, 256, 0, stream>>>(query, kvst, Xq_hi, Xq_lo, Xkv_hi, Xkv_lo);
  k_convw<<<dim3(32,32,6), 256, 0, stream>>>(Wq, Wk, Wv, Wpk, Wpq, Wo, Wt);
  k_lnrel<<<64, 256, 0, stream>>>(rel, lng, lnb, reln_hi, reln_lo);
  k_bucket<<<8, 256, 0, stream>>>(idxt);

  // q GEMM first (Xq region is reused by v GEMM's output)
  k_gemm<0><<<256, 256, 0, stream>>>(Xq_hi,  Xq_lo,  Wt + 0*2097152, Wt + 0*2097152 + 1048576, bq, qbuf_hi, qbuf_lo, nullptr);
  k_gemm<0><<<256, 256, 0, stream>>>(Xkv_hi, Xkv_lo, Wt + 1*2097152, Wt + 1*2097152 + 1048576, bk, kbuf_hi, kbuf_lo, nullptr);
  k_gemm<1><<<256, 256, 0, stream>>>(Xkv_hi, Xkv_lo, Wt + 2*2097152, Wt + 2*2097152 + 1048576, bv, vtb_hi, vtb_lo, nullptr);

  k_pos<<<dim3(16,2), 256, 0, stream>>>(reln_hi, reln_lo, Wt, bpk, bpq, posk_hi, posk_lo, posq_hi, posq_lo);
  k_cp<<<dim3(16,64,2), 256, 0, stream>>>(qbuf_hi, qbuf_lo, kbuf_hi, kbuf_lo,
                                          posk_hi, posk_lo, posq_hi, posq_lo, c2p, p2c);

  k_attn<<<dim3(16,64), 256, 0, stream>>>(qbuf_hi, kbuf_hi, vtb_hi,
                                          c2p, p2c, idxt, mask, ctx_hi, ctx_lo);

  k_gemm<2><<<256, 256, 0, stream>>>(ctx_hi, ctx_lo, Wt + 5*2097152, Wt + 5*2097152 + 1048576, bo, nullptr, nullptr, (float*)d_out);
}

// Round 4
// 332.979 us; speedup vs baseline: 1.4976x; 1.2624x over previous
//
#include <hip/hip_runtime.h>
#include <cstdint>
#include <math.h>

typedef unsigned short us;
typedef __attribute__((ext_vector_type(8))) __bf16 bf16x8;
typedef __attribute__((ext_vector_type(8))) unsigned short ushort8;
typedef __attribute__((ext_vector_type(4))) float f32x4;

__device__ __forceinline__ us f2bf(float x){
  union { float f; unsigned int u; } v; v.f = x;
  unsigned int r = v.u + 0x7FFFu + ((v.u >> 16) & 1u);   // RNE
  return (us)(r >> 16);
}
__device__ __forceinline__ float b2f(us u){
  union { unsigned int u; float f; } v; v.u = ((unsigned int)u) << 16; return v.f;
}
__device__ __forceinline__ void split2(float x, us& hi, us& lo){
  hi = f2bf(x); lo = f2bf(x - b2f(hi));
}
__device__ __forceinline__ f32x4 fzero(){ f32x4 v; v.x=0.f; v.y=0.f; v.z=0.f; v.w=0.f; return v; }
__device__ __forceinline__ f32x4 mfma16(bf16x8 a, bf16x8 b, f32x4 c){
  return __builtin_amdgcn_mfma_f32_16x16x32_bf16(a, b, c, 0, 0, 0);
}
__device__ __forceinline__ void gload_lds16(const void* g, void* l){
  __builtin_amdgcn_global_load_lds(
      (const __attribute__((address_space(1))) unsigned int*)(uintptr_t)g,
      (__attribute__((address_space(3))) unsigned int*)(uintptr_t)l,
      16, 0, 0);
}

// ---------------- 1: fp32 -> bf16 hi/lo split of inputs ----------------
__global__ __launch_bounds__(256) void k_convx(const float* __restrict__ xq,
                                               const float* __restrict__ xkv,
                                               us* __restrict__ qhi, us* __restrict__ qlo,
                                               us* __restrict__ kvhi, us* __restrict__ kvlo)
{
  int i = blockIdx.x * 256 + threadIdx.x;   // float4 units, 2M total
  const float* src; us *dh, *dl;
  if (i < 1048576) { src = xq  + (size_t)i*4;            dh = qhi  + (size_t)i*4;            dl = qlo  + (size_t)i*4; }
  else             { src = xkv + (size_t)(i-1048576)*4;  dh = kvhi + (size_t)(i-1048576)*4;  dl = kvlo + (size_t)(i-1048576)*4; }
  f32x4 v = *(const f32x4*)src;
  us h0,l0,h1,l1,h2,l2,h3,l3;
  split2(v.x,h0,l0); split2(v.y,h1,l1); split2(v.z,h2,l2); split2(v.w,h3,l3);
  dh[0]=h0; dh[1]=h1; dh[2]=h2; dh[3]=h3;
  dl[0]=l0; dl[1]=l1; dl[2]=l2; dl[3]=l3;
}

// ---------------- 2: weight transpose + hi/lo split: Wt[n][k] ----------------
__global__ __launch_bounds__(256) void k_convw(const float* w0, const float* w1, const float* w2,
                                               const float* w3, const float* w4, const float* w5,
                                               us* __restrict__ wt)
{
  __shared__ float tile[32][33];
  int z = blockIdx.z;
  const float* W = (z==0)?w0:(z==1)?w1:(z==2)?w2:(z==3)?w3:(z==4)?w4:w5;
  us* dst_hi = wt + (size_t)z * 2097152;
  us* dst_lo = dst_hi + 1048576;
  int n0 = blockIdx.x * 32, k0 = blockIdx.y * 32;
  int c = threadIdx.x & 31, r = threadIdx.x >> 5;
#pragma unroll
  for (int i = 0; i < 4; i++)
    tile[r + i*8][c] = W[(size_t)(k0 + r + i*8)*1024 + n0 + c];
  __syncthreads();
#pragma unroll
  for (int i = 0; i < 4; i++){
    int nn = r + i*8;
    us h,l; split2(tile[c][nn], h, l);
    dst_hi[(size_t)(n0 + nn)*1024 + k0 + c] = h;
    dst_lo[(size_t)(n0 + nn)*1024 + k0 + c] = l;
  }
}

// ---------------- 3: layernorm(rel_emb) -> bf16 hi/lo ----------------
__global__ __launch_bounds__(256) void k_lnrel(const float* __restrict__ rel,
                                               const float* __restrict__ g,
                                               const float* __restrict__ b,
                                               us* __restrict__ out_hi,
                                               us* __restrict__ out_lo)
{
  __shared__ float sm[8];
  int row = blockIdx.x, t = threadIdx.x;
  const float* x = rel + (size_t)row * 1024;
  float v[4]; float s = 0.f, ss = 0.f;
#pragma unroll
  for (int i=0;i<4;i++){ v[i] = x[t + 256*i]; s += v[i]; ss += v[i]*v[i]; }
  for (int o=32;o;o>>=1){ s += __shfl_xor(s,o); ss += __shfl_xor(ss,o); }
  int w = t >> 6;
  if ((t & 63) == 0){ sm[w] = s; sm[4+w] = ss; }
  __syncthreads();
  s  = sm[0]+sm[1]+sm[2]+sm[3];
  ss = sm[4]+sm[5]+sm[6]+sm[7];
  float mu  = s  * (1.0f/1024.0f);
  float var = ss * (1.0f/1024.0f) - mu*mu;
  float rs  = rsqrtf(var + 1e-5f);
#pragma unroll
  for (int i=0;i<4;i++){
    int cc = t + 256*i;
    float r = (v[i]-mu)*rs*g[cc] + b[cc];
    us h,l; split2(r,h,l);
    out_hi[(size_t)row*1024 + cc] = h;
    out_lo[(size_t)row*1024 + cc] = l;
  }
}

// ---------------- 4: log-bucket idx table (mirrors numpy f32 arithmetic) ----------------
__global__ void k_bucket(signed char* __restrict__ idxt)
{
  int i = blockIdx.x * 256 + threadIdx.x;
  if (i >= 2047) return;
  int d = i - 1023;
  int ad = d < 0 ? -d : d;
  int abspos = (d < 16 && d > -16) ? 15 : ad;
  int bucket;
  if (abspos <= 16) bucket = d;
  else {
    float num = (float)log((double)abspos * 0.0625);   // correctly-rounded f32 log
    float den = (float)log(7.9375);
    float lp = ceilf(num / den * 15.0f) + 16.0f;
    bucket = (int)lp * (d > 0 ? 1 : -1);
  }
  int s = bucket + 32;
  s = s < 0 ? 0 : (s > 63 ? 63 : s);
  idxt[i] = (signed char)s;
}

// ---------------- 5: split GEMM: NSEG products over hi/lo pairs ----------------
// MODE 0: out bf16 hi/lo [B,H,T,HD]; MODE 1: out bf16 hi/lo [B,H,HD,T]; MODE 2: fp32 [M][N]
// NSEG=1: Ahi*Bhi. NSEG=3: + Ahi*Blo + Alo*Bhi.
template<int MODE, int NSEG>
__global__ __launch_bounds__(256) void k_gemm(const us* __restrict__ A_hi, const us* __restrict__ A_lo,
                                              const us* __restrict__ B_hi, const us* __restrict__ B_lo,
                                              const float* __restrict__ bias,
                                              us* __restrict__ out_hi, us* __restrict__ out_lo,
                                              float* __restrict__ out_f)
{
  __shared__ __align__(16) us a_lds[2][4096];
  __shared__ __align__(16) us b_lds[2][4096];
  int bid = blockIdx.x;
  int wg = (bid & 7) * 32 + (bid >> 3);        // XCD swizzle (256 % 8 == 0)
  int mt = wg >> 3, nt = wg & 7;
  int m0 = mt * 128, n0 = nt * 128;
  int t = threadIdx.x, w = t >> 6, lane = t & 63, lg = lane >> 4, li = lane & 15;
  int wm = w >> 1, wn = w & 1;
  const int NKT = NSEG * 32;
  f32x4 acc[4][4];
#pragma unroll
  for (int i=0;i<4;i++)
#pragma unroll
    for (int j=0;j<4;j++) acc[i][j] = fzero();

  auto stage = [&](int buf, int kt){
    int seg = kt >> 5, k0 = (kt & 31) * 32;
    const us* Ap = (seg == 2) ? A_lo : A_hi;
    const us* Bp = (seg == 1) ? B_lo : B_hi;
#pragma unroll
    for (int c = 0; c < 2; c++){
      int sbase = c*256 + w*64;
      int slot = sbase + lane;
      int g = slot ^ ((slot >> 3) & 7);
      int r = g >> 2, kc = g & 3;
      gload_lds16(Ap + (size_t)(m0 + r)*1024 + k0 + kc*8, (char*)&a_lds[buf][0] + sbase*16);
      gload_lds16(Bp + (size_t)(n0 + r)*1024 + k0 + kc*8, (char*)&b_lds[buf][0] + sbase*16);
    }
  };

  stage(0, 0);
  __syncthreads();
  int buf = 0;
  for (int kt = 0; kt < NKT; kt++){
    if (kt + 1 < NKT) stage(buf ^ 1, kt + 1);
    bf16x8 af[4], bfv[4];
#pragma unroll
    for (int mi=0;mi<4;mi++){
      int r = wm*64 + mi*16 + li;
      int s = (r*4 + lg); s ^= ((s >> 3) & 7);
      af[mi] = *(const bf16x8*)((char*)&a_lds[buf][0] + s*16);
    }
#pragma unroll
    for (int ni=0;ni<4;ni++){
      int r = wn*64 + ni*16 + li;
      int s = (r*4 + lg); s ^= ((s >> 3) & 7);
      bfv[ni] = *(const bf16x8*)((char*)&b_lds[buf][0] + s*16);
    }
#pragma unroll
    for (int mi=0;mi<4;mi++)
#pragma unroll
      for (int ni=0;ni<4;ni++)
        acc[mi][ni] = mfma16(af[mi], bfv[ni], acc[mi][ni]);
    __syncthreads();
    buf ^= 1;
  }

#pragma unroll
  for (int ni=0;ni<4;ni++){
    int n = n0 + wn*64 + ni*16 + li;
    float bn = bias[n];
    int hh = n >> 6, hd = n & 63;
#pragma unroll
    for (int mi=0;mi<4;mi++){
      int mb = m0 + wm*64 + mi*16 + lg*4;
#pragma unroll
      for (int j=0;j<4;j++){
        int m = mb + j;
        float val = acc[mi][ni][j] + bn;
        if (MODE == 2){
          out_f[(size_t)m*1024 + n] = val;
        } else {
          us h,l; split2(val,h,l);
          size_t idx;
          int bb = m >> 10, tp = m & 1023;
          if (MODE == 0) idx = (((size_t)(bb*16 + hh))*1024 + tp)*64 + hd;
          else           idx = (((size_t)(bb*16 + hh))*64 + hd)*1024 + tp;
          out_hi[idx] = h; out_lo[idx] = l;
        }
      }
    }
  }
}

// ---------------- 6: pos_k/pos_q = LN(rel) @ Wp + bp (3 products), out [H][2S][HD] hi/lo ----------------
__global__ __launch_bounds__(256) void k_pos(const us* __restrict__ reln_hi, const us* __restrict__ reln_lo,
                                             const us* __restrict__ wt,
                                             const float* __restrict__ bpk, const float* __restrict__ bpq,
                                             us* __restrict__ posk_hi, us* __restrict__ posk_lo,
                                             us* __restrict__ posq_hi, us* __restrict__ posq_lo)
{
  int ntile = blockIdx.x;            // 0..15
  int z = blockIdx.y;                // 0: pk (weight idx 3), 1: pq (weight idx 4)
  const us* W_hi = wt + (size_t)(3 + z) * 2097152;
  const us* W_lo = W_hi + 1048576;
  const float* bias = z ? bpq : bpk;
  us* out_hi = z ? posq_hi : posk_hi;
  us* out_lo = z ? posq_lo : posk_lo;
  int t = threadIdx.x, w = t >> 6, lane = t & 63, lg = lane >> 4, li = lane & 15;
  f32x4 acc[4];
#pragma unroll
  for (int i=0;i<4;i++) acc[i] = fzero();
  int srow = w*16 + li;
  for (int kt = 0; kt < 96; kt++){
    int seg = kt >> 5, k0 = (kt & 31)*32 + lg*8;
    const us* Ap = (seg == 2) ? reln_lo : reln_hi;
    const us* Bp = (seg == 1) ? W_lo : W_hi;
    bf16x8 a = *(const bf16x8*)(Ap + (size_t)srow*1024 + k0);
#pragma unroll
    for (int nf=0; nf<4; nf++){
      int n = ntile*64 + nf*16 + li;
      bf16x8 b = *(const bf16x8*)(Bp + (size_t)n*1024 + k0);
      acc[nf] = mfma16(a, b, acc[nf]);
    }
  }
#pragma unroll
  for (int nf=0;nf<4;nf++){
    int n = ntile*64 + nf*16 + li;
    float bn = bias[n];
    int h = n >> 6, hd = n & 63;
#pragma unroll
    for (int j=0;j<4;j++){
      int s = w*16 + lg*4 + j;
      us hh,ll; split2(acc[nf][j] + bn, hh, ll);
      out_hi[(size_t)h*4096 + s*64 + hd] = hh;
      out_lo[(size_t)h*4096 + s*64 + hd] = ll;
    }
  }
}

// ---------------- 7: c2p[b,h,q,s] / p2c[b,h,k,s] (3 products, bf16 out) ----------------
__global__ __launch_bounds__(256) void k_cp(const us* __restrict__ q_hi, const us* __restrict__ q_lo,
                                            const us* __restrict__ k_hi, const us* __restrict__ k_lo,
                                            const us* __restrict__ pk_hi, const us* __restrict__ pk_lo,
                                            const us* __restrict__ pq_hi, const us* __restrict__ pq_lo,
                                            us* __restrict__ c2p, us* __restrict__ p2c)
{
  int qt = blockIdx.x, bh = blockIdx.y, z = blockIdx.z;
  const us* X_hi = z ? k_hi : q_hi;
  const us* X_lo = z ? k_lo : q_lo;
  const us* P_hi = z ? pq_hi : pk_hi;
  const us* P_lo = z ? pq_lo : pk_lo;
  us* out = z ? p2c : c2p;
  int h = bh & 15;
  int t = threadIdx.x, w = t >> 6, lane = t & 63, lg = lane >> 4, li = lane & 15;
  f32x4 acc[4];
#pragma unroll
  for (int i=0;i<4;i++) acc[i] = fzero();
  size_t row = (size_t)bh*1024 + qt*64 + w*16 + li;
#pragma unroll
  for (int kk=0;kk<2;kk++){
    int k = kk*32 + lg*8;
    bf16x8 ah = *(const bf16x8*)(X_hi + row*64 + k);
    bf16x8 al = *(const bf16x8*)(X_lo + row*64 + k);
#pragma unroll
    for (int nf=0;nf<4;nf++){
      int s = nf*16 + li;
      bf16x8 bh_ = *(const bf16x8*)(P_hi + (size_t)h*4096 + s*64 + k);
      bf16x8 bl_ = *(const bf16x8*)(P_lo + (size_t)h*4096 + s*64 + k);
      acc[nf] = mfma16(ah, bh_, acc[nf]);
      acc[nf] = mfma16(ah, bl_, acc[nf]);
      acc[nf] = mfma16(al, bh_, acc[nf]);
    }
  }
  size_t obase = ((size_t)bh*1024 + qt*64 + w*16 + lg*4) * 64;
#pragma unroll
  for (int nf=0;nf<4;nf++)
#pragma unroll
    for (int j=0;j<4;j++)
      out[obase + (size_t)j*64 + nf*16 + li] = f2bf(acc[nf][j]);
}

// ---------------- 8: fused attention: QBLK=128, one-pass softmax (no running max) ----------------
// Scores bounded (|s| <~ 5 for this op's scales); exp never overflows fp32.
__global__ __launch_bounds__(256) void k_attn(const us* __restrict__ qhi,
                                              const us* __restrict__ khi,
                                              const us* __restrict__ vhi,
                                              const us* __restrict__ c2p, const us* __restrict__ p2c,
                                              const signed char* __restrict__ idxt,
                                              const unsigned char* __restrict__ mask,
                                              us* __restrict__ ctx_hi, us* __restrict__ ctx_lo)
{
  __shared__ __align__(16) us khi_lds[4096], vhi_lds[4096];
  __shared__ __align__(16) us c2p_lds[128*72], p2c_lds[64*72];   // padded rows: 144B stride
  __shared__ __align__(16) us p_lds[4][1024];
  __shared__ signed char idx_lds[2048];

  const int qt = blockIdx.x, bh = blockIdx.y;   // qt: 0..7
  const int b = bh >> 4, h = bh & 15;
  const int t = threadIdx.x, w = t >> 6, lane = t & 63, lg = lane >> 4, li = lane & 15;
  const int q0 = qt * 128;

  for (int i = t; i < 2047; i += 256) idx_lds[i] = idxt[i];
  {
    const us* src = c2p + ((size_t)bh*1024 + q0) * 64;
#pragma unroll
    for (int c = 0; c < 4; c++){
      int f = c*256 + t, r = f >> 3, kc = f & 7;
      *(ushort8*)&c2p_lds[r*72 + kc*8] = *(const ushort8*)(src + r*64 + kc*8);
    }
  }
  bf16x8 qfh[2][2];
#pragma unroll
  for (int rf=0;rf<2;rf++){
    const us* qph = qhi + ((size_t)bh*1024 + q0 + rf*64 + w*16 + li)*64 + lg*8;
    qfh[rf][0] = *(const bf16x8*)(qph); qfh[rf][1] = *(const bf16x8*)(qph + 32);
  }
  float lrow[2][4];
  f32x4 accO[2][4];
#pragma unroll
  for (int rf=0;rf<2;rf++)
#pragma unroll
    for (int j=0;j<4;j++){ lrow[rf][j] = 0.f; accO[rf][j] = fzero(); }

  const float inv_scale = 0.07216878364870322f;  // 1/sqrt(64*3)
  const float inv_bias  = 0.08838834764831845f;  // 1/sqrt(64*2)
  const unsigned char* mptr = mask + b*1024;

  for (int kt = 0; kt < 16; kt++){
    const int k0 = kt * 64;
    __syncthreads();
    // stage K hi, V hi (each 64x64 bf16 = 512 chunks of 16B), swizzled
#pragma unroll
    for (int c = 0; c < 4; c++){
      int f = c*256 + t;
      int tile = f >> 9;
      int chunk = f & 511, r = chunk >> 3, kc = chunk & 7;
      const us* src; us* dst;
      if (tile == 0){ src = khi + ((size_t)bh*1024 + k0 + r)*64 + kc*8; dst = khi_lds; }
      else          { src = vhi + ((size_t)bh*64 + r)*1024 + k0 + kc*8; dst = vhi_lds; }
      *(ushort8*)&dst[r*64 + ((kc ^ (r & 7))*8)] = *(const ushort8*)src;
    }
    {
      const us* src = p2c + ((size_t)bh*1024 + k0)*64;
#pragma unroll
      for (int c = 0; c < 2; c++){
        int f = c*256 + t, r = f >> 3, kc = f & 7;
        *(ushort8*)&p2c_lds[r*72 + kc*8] = *(const ushort8*)(src + r*64 + kc*8);
      }
    }
    __syncthreads();

#pragma unroll
    for (int rf = 0; rf < 2; rf++){
      // QK^T single product
      f32x4 sfr[4];
#pragma unroll
      for (int nf=0;nf<4;nf++) sfr[nf] = fzero();
#pragma unroll
      for (int kk=0; kk<2; kk++){
        int kc = kk*4 + lg;
#pragma unroll
        for (int nf=0; nf<4; nf++){
          int r = nf*16 + li;
          bf16x8 bh_ = *(const bf16x8*)&khi_lds[r*64 + ((kc ^ (r & 7))*8)];
          sfr[nf] = mfma16(qfh[rf][kk], bh_, sfr[nf]);
        }
      }
      // scale + rel-pos bias + mask + exp (one-pass, no max)
      us* pl = &p_lds[w][0];
#pragma unroll
      for (int nf=0; nf<4; nf++){
        int kloc = nf*16 + li;
        bool mk = mptr[k0 + kloc] != 0;
        int col = nf*16 + li;
#pragma unroll
        for (int j=0;j<4;j++){
          int qloc = rf*64 + w*16 + lg*4 + j;     // row within block's 128
          int d = (q0 + qloc) - (k0 + kloc);
          int idx = (int)idx_lds[d + 1023];
          float s = sfr[nf][j]*inv_scale
                  + (b2f(c2p_lds[qloc*72 + idx]) + b2f(p2c_lds[kloc*72 + idx]))*inv_bias;
          float p = mk ? 0.f : __expf(s);
          lrow[rf][j] += p;
          int row = lg*4 + j;
          pl[row*64 + ((col & 7) | ((((col >> 3) ^ (row & 7))) << 3))] = f2bf(p);
        }
      }
      // PV single product (p_lds wave-private; same-wave DS ordering)
#pragma unroll
      for (int kk=0;kk<2;kk++){
        int kc = kk*4 + lg;
        bf16x8 af = *(const bf16x8*)((char*)pl + li*128 + ((kc ^ (li & 7)) * 16));
#pragma unroll
        for (int nf=0;nf<4;nf++){
          int r = nf*16 + li;
          bf16x8 bh_ = *(const bf16x8*)&vhi_lds[r*64 + ((kc ^ (r & 7))*8)];
          accO[rf][nf] = mfma16(af, bh_, accO[rf][nf]);
        }
      }
    }
  }

#pragma unroll
  for (int rf=0;rf<2;rf++)
    for (int o=1;o<16;o<<=1)
#pragma unroll
      for (int j=0;j<4;j++)
        lrow[rf][j] += __shfl_xor(lrow[rf][j], o);
#pragma unroll
  for (int rf=0;rf<2;rf++)
#pragma unroll
    for (int nf=0;nf<4;nf++)
#pragma unroll
      for (int j=0;j<4;j++){
        int qloc = rf*64 + w*16 + lg*4 + j;
        float o = accO[rf][nf][j] / lrow[rf][j];
        size_t idx = ((size_t)(b*1024 + q0 + qloc))*1024 + h*64 + nf*16 + li;
        us hh,ll; split2(o,hh,ll);
        ctx_hi[idx] = hh; ctx_lo[idx] = ll;
      }
}

// ---------------- launch ----------------
extern "C" void kernel_launch(void* const* d_in, const int* in_sizes, int n_in,
                              void* d_out, int out_size, void* d_ws, size_t ws_size,
                              hipStream_t stream)
{
  (void)in_sizes; (void)n_in; (void)out_size; (void)ws_size;
  const float* query = (const float*)d_in[0];
  const float* kvst  = (const float*)d_in[1];
  const unsigned char* mask = (const unsigned char*)d_in[2];
  const float* Wq = (const float*)d_in[3];  const float* bq = (const float*)d_in[4];
  const float* Wk = (const float*)d_in[5];  const float* bk = (const float*)d_in[6];
  const float* Wv = (const float*)d_in[7];  const float* bv = (const float*)d_in[8];
  const float* Wo = (const float*)d_in[9];  const float* bo = (const float*)d_in[10];
  const float* rel = (const float*)d_in[11];
  const float* lng = (const float*)d_in[12]; const float* lnb = (const float*)d_in[13];
  const float* Wpk = (const float*)d_in[14]; const float* bpk = (const float*)d_in[15];
  const float* Wpq = (const float*)d_in[16]; const float* bpq = (const float*)d_in[17];

  char* ws = (char*)d_ws;
  const size_t MB = 1024*1024;
  // [0..16)  Xq hi/lo, later vtb hi/lo
  us* Xq_hi  = (us*)(ws + 0);      us* Xq_lo  = (us*)(ws + 8*MB);
  us* vtb_hi = (us*)(ws + 0);      us* vtb_lo = (us*)(ws + 8*MB);
  // [16..32) Xkv hi/lo, later c2p/p2c (bf16)
  us* Xkv_hi = (us*)(ws + 16*MB);  us* Xkv_lo = (us*)(ws + 24*MB);
  us* c2p    = (us*)(ws + 16*MB);  us* p2c    = (us*)(ws + 24*MB);
  // [32..56) weights (z*4MB: hi, lo): 0 Wq, 1 Wk, 2 Wv, 3 Wpk, 4 Wpq, 5 Wo
  us* Wt = (us*)(ws + 32*MB);
  // [32..48) reused for ctx hi/lo after k_pos + QKV GEMMs are done
  us* ctx_hi = (us*)(ws + 32*MB);  us* ctx_lo = (us*)(ws + 40*MB);
  // [56..57) small
  us* reln_hi = (us*)(ws + 56*MB);
  us* reln_lo = (us*)(ws + 56*MB + 128*1024);
  us* posk_hi = (us*)(ws + 56*MB + 256*1024);
  us* posk_lo = (us*)(ws + 56*MB + 384*1024);
  us* posq_hi = (us*)(ws + 56*MB + 512*1024);
  us* posq_lo = (us*)(ws + 56*MB + 640*1024);
  signed char* idxt = (signed char*)(ws + 56*MB + 768*1024);
  // [57..89) q/k buffers hi/lo
  us* qbuf_hi = (us*)(ws + 57*MB); us* qbuf_lo = (us*)(ws + 65*MB);
  us* kbuf_hi = (us*)(ws + 73*MB); us* kbuf_lo = (us*)(ws + 81*MB);

  k_convx<<<8192, 256, 0, stream>>>(query, kvst, Xq_hi, Xq_lo, Xkv_hi, Xkv_lo);
  k_convw<<<dim3(32,32,6), 256, 0, stream>>>(Wq, Wk, Wv, Wpk, Wpq, Wo, Wt);
  k_lnrel<<<64, 256, 0, stream>>>(rel, lng, lnb, reln_hi, reln_lo);
  k_bucket<<<8, 256, 0, stream>>>(idxt);

  // Q,K projections: single product (score path, softmax-attenuated).
  // V: 3 products (coherent relative path to output).
  k_gemm<0,1><<<256, 256, 0, stream>>>(Xq_hi,  Xq_lo,  Wt + 0*2097152, Wt + 0*2097152 + 1048576, bq, qbuf_hi, qbuf_lo, nullptr);
  k_gemm<0,1><<<256, 256, 0, stream>>>(Xkv_hi, Xkv_lo, Wt + 1*2097152, Wt + 1*2097152 + 1048576, bk, kbuf_hi, kbuf_lo, nullptr);
  k_gemm<1,3><<<256, 256, 0, stream>>>(Xkv_hi, Xkv_lo, Wt + 2*2097152, Wt + 2*2097152 + 1048576, bv, vtb_hi, vtb_lo, nullptr);

  k_pos<<<dim3(16,2), 256, 0, stream>>>(reln_hi, reln_lo, Wt, bpk, bpq, posk_hi, posk_lo, posq_hi, posq_lo);
  k_cp<<<dim3(16,64,2), 256, 0, stream>>>(qbuf_hi, qbuf_lo, kbuf_hi, kbuf_lo,
                                          posk_hi, posk_lo, posq_hi, posq_lo, c2p, p2c);

  k_attn<<<dim3(8,64), 256, 0, stream>>>(qbuf_hi, kbuf_hi, vtb_hi,
                                         c2p, p2c, idxt, mask, ctx_hi, ctx_lo);

  k_gemm<2,3><<<256, 256, 0, stream>>>(ctx_hi, ctx_lo, Wt + 5*2097152, Wt + 5*2097152 + 1048576, bo, nullptr, nullptr, (float*)d_out);
}

// Round 5
// 246.592 us; speedup vs baseline: 2.0222x; 1.3503x over previous
//
#include <hip/hip_runtime.h>
#include <cstdint>
#include <math.h>

typedef unsigned short us;
typedef __attribute__((ext_vector_type(8))) __bf16 bf16x8;
typedef __attribute__((ext_vector_type(8))) unsigned short ushort8;
typedef __attribute__((ext_vector_type(4))) float f32x4;

__device__ __forceinline__ us f2bf(float x){
  union { float f; unsigned int u; } v; v.f = x;
  unsigned int r = v.u + 0x7FFFu + ((v.u >> 16) & 1u);   // RNE
  return (us)(r >> 16);
}
__device__ __forceinline__ float b2f(us u){
  union { unsigned int u; float f; } v; v.u = ((unsigned int)u) << 16; return v.f;
}
__device__ __forceinline__ void split2(float x, us& hi, us& lo){
  hi = f2bf(x); lo = f2bf(x - b2f(hi));
}
__device__ __forceinline__ f32x4 fzero(){ f32x4 v; v.x=0.f; v.y=0.f; v.z=0.f; v.w=0.f; return v; }
__device__ __forceinline__ f32x4 mfma16(bf16x8 a, bf16x8 b, f32x4 c){
  return __builtin_amdgcn_mfma_f32_16x16x32_bf16(a, b, c, 0, 0, 0);
}
__device__ __forceinline__ void gload_lds16(const void* g, void* l){
  __builtin_amdgcn_global_load_lds(
      (const __attribute__((address_space(1))) unsigned int*)(uintptr_t)g,
      (__attribute__((address_space(3))) unsigned int*)(uintptr_t)l,
      16, 0, 0);
}

// exp2-folded scales
#define QS2 (0.07216878364870322f * 1.4426950408889634f)   // 1/sqrt(192) * log2(e)
#define BS  (0.08838834764831845f * 1.4426950408889634f)   // 1/sqrt(128) * log2(e)

// ---------------- 1: fp32 -> bf16 split (q: hi only; kv: hi/lo) ----------------
__global__ __launch_bounds__(256) void k_convx(const float* __restrict__ xq,
                                               const float* __restrict__ xkv,
                                               us* __restrict__ qhi,
                                               us* __restrict__ kvhi, us* __restrict__ kvlo)
{
  int i = blockIdx.x * 256 + threadIdx.x;   // float4 units, 2M total
  if (i < 1048576){
    f32x4 v = *(const f32x4*)(xq + (size_t)i*4);
    us* dh = qhi + (size_t)i*4;
    dh[0]=f2bf(v.x); dh[1]=f2bf(v.y); dh[2]=f2bf(v.z); dh[3]=f2bf(v.w);
  } else {
    int j = i - 1048576;
    f32x4 v = *(const f32x4*)(xkv + (size_t)j*4);
    us* dh = kvhi + (size_t)j*4; us* dl = kvlo + (size_t)j*4;
    us h0,l0,h1,l1,h2,l2,h3,l3;
    split2(v.x,h0,l0); split2(v.y,h1,l1); split2(v.z,h2,l2); split2(v.w,h3,l3);
    dh[0]=h0; dh[1]=h1; dh[2]=h2; dh[3]=h3;
    dl[0]=l0; dl[1]=l1; dl[2]=l2; dl[3]=l3;
  }
}

// ---------------- 2: weight transpose + split: Wt[n][k] (lo only for Wv,Wo) ----------------
__global__ __launch_bounds__(256) void k_convw(const float* w0, const float* w1, const float* w2,
                                               const float* w3, const float* w4, const float* w5,
                                               us* __restrict__ wt)
{
  __shared__ float tile[32][33];
  int z = blockIdx.z;
  const float* W = (z==0)?w0:(z==1)?w1:(z==2)?w2:(z==3)?w3:(z==4)?w4:w5;
  us* dst_hi = wt + (size_t)z * 2097152;
  us* dst_lo = dst_hi + 1048576;
  bool wlo = (z == 2) || (z == 5);
  int n0 = blockIdx.x * 32, k0 = blockIdx.y * 32;
  int c = threadIdx.x & 31, r = threadIdx.x >> 5;
#pragma unroll
  for (int i = 0; i < 4; i++)
    tile[r + i*8][c] = W[(size_t)(k0 + r + i*8)*1024 + n0 + c];
  __syncthreads();
#pragma unroll
  for (int i = 0; i < 4; i++){
    int nn = r + i*8;
    us h,l; split2(tile[c][nn], h, l);
    dst_hi[(size_t)(n0 + nn)*1024 + k0 + c] = h;
    if (wlo) dst_lo[(size_t)(n0 + nn)*1024 + k0 + c] = l;
  }
}

// ---------------- 3: layernorm(rel_emb) -> bf16 hi ----------------
__global__ __launch_bounds__(256) void k_lnrel(const float* __restrict__ rel,
                                               const float* __restrict__ g,
                                               const float* __restrict__ b,
                                               us* __restrict__ out_hi)
{
  __shared__ float sm[8];
  int row = blockIdx.x, t = threadIdx.x;
  const float* x = rel + (size_t)row * 1024;
  float v[4]; float s = 0.f, ss = 0.f;
#pragma unroll
  for (int i=0;i<4;i++){ v[i] = x[t + 256*i]; s += v[i]; ss += v[i]*v[i]; }
  for (int o=32;o;o>>=1){ s += __shfl_xor(s,o); ss += __shfl_xor(ss,o); }
  int w = t >> 6;
  if ((t & 63) == 0){ sm[w] = s; sm[4+w] = ss; }
  __syncthreads();
  s  = sm[0]+sm[1]+sm[2]+sm[3];
  ss = sm[4]+sm[5]+sm[6]+sm[7];
  float mu  = s  * (1.0f/1024.0f);
  float var = ss * (1.0f/1024.0f) - mu*mu;
  float rs  = rsqrtf(var + 1e-5f);
#pragma unroll
  for (int i=0;i<4;i++){
    int cc = t + 256*i;
    out_hi[(size_t)row*1024 + cc] = f2bf((v[i]-mu)*rs*g[cc] + b[cc]);
  }
}

// ---------------- 4: log-bucket idx table (mirrors numpy f32 arithmetic) ----------------
__global__ void k_bucket(signed char* __restrict__ idxt)
{
  int i = blockIdx.x * 256 + threadIdx.x;
  if (i >= 2047) return;
  int d = i - 1023;
  int ad = d < 0 ? -d : d;
  int abspos = (d < 16 && d > -16) ? 15 : ad;
  int bucket;
  if (abspos <= 16) bucket = d;
  else {
    float num = (float)log((double)abspos * 0.0625);
    float den = (float)log(7.9375);
    float lp = ceilf(num / den * 15.0f) + 16.0f;
    bucket = (int)lp * (d > 0 ? 1 : -1);
  }
  int s = bucket + 32;
  s = s < 0 ? 0 : (s > 63 ? 63 : s);
  idxt[i] = (signed char)s;
}

// ---------------- 5: split GEMM: NSEG products over hi/lo pairs ----------------
// MODE 0: out bf16 [B,H,T,HD]; MODE 1: out bf16 [B,H,HD,T]; MODE 2: fp32 [M][N]
// seg 0: Ahi*Bhi; seg 1: Ahi*Blo; seg 2: Alo*Bhi
template<int MODE, int NSEG>
__global__ __launch_bounds__(256) void k_gemm(const us* __restrict__ A_hi, const us* __restrict__ A_lo,
                                              const us* __restrict__ B_hi, const us* __restrict__ B_lo,
                                              const float* __restrict__ bias,
                                              us* __restrict__ out_hi,
                                              float* __restrict__ out_f)
{
  __shared__ __align__(16) us a_lds[2][4096];
  __shared__ __align__(16) us b_lds[2][4096];
  int bid = blockIdx.x;
  int wg = (bid & 7) * 32 + (bid >> 3);        // XCD swizzle (256 % 8 == 0)
  int mt = wg >> 3, nt = wg & 7;
  int m0 = mt * 128, n0 = nt * 128;
  int t = threadIdx.x, w = t >> 6, lane = t & 63, lg = lane >> 4, li = lane & 15;
  int wm = w >> 1, wn = w & 1;
  const int NKT = NSEG * 32;
  f32x4 acc[4][4];
#pragma unroll
  for (int i=0;i<4;i++)
#pragma unroll
    for (int j=0;j<4;j++) acc[i][j] = fzero();

  auto stage = [&](int buf, int kt){
    int seg = kt >> 5, k0 = (kt & 31) * 32;
    const us* Ap = (seg == 2) ? A_lo : A_hi;
    const us* Bp = (seg == 1) ? B_lo : B_hi;
#pragma unroll
    for (int c = 0; c < 2; c++){
      int sbase = c*256 + w*64;
      int slot = sbase + lane;
      int g = slot ^ ((slot >> 3) & 7);
      int r = g >> 2, kc = g & 3;
      gload_lds16(Ap + (size_t)(m0 + r)*1024 + k0 + kc*8, (char*)&a_lds[buf][0] + sbase*16);
      gload_lds16(Bp + (size_t)(n0 + r)*1024 + k0 + kc*8, (char*)&b_lds[buf][0] + sbase*16);
    }
  };

  stage(0, 0);
  __syncthreads();
  int buf = 0;
  for (int kt = 0; kt < NKT; kt++){
    if (kt + 1 < NKT) stage(buf ^ 1, kt + 1);
    bf16x8 af[4], bfv[4];
#pragma unroll
    for (int mi=0;mi<4;mi++){
      int r = wm*64 + mi*16 + li;
      int s = (r*4 + lg); s ^= ((s >> 3) & 7);
      af[mi] = *(const bf16x8*)((char*)&a_lds[buf][0] + s*16);
    }
#pragma unroll
    for (int ni=0;ni<4;ni++){
      int r = wn*64 + ni*16 + li;
      int s = (r*4 + lg); s ^= ((s >> 3) & 7);
      bfv[ni] = *(const bf16x8*)((char*)&b_lds[buf][0] + s*16);
    }
#pragma unroll
    for (int mi=0;mi<4;mi++)
#pragma unroll
      for (int ni=0;ni<4;ni++)
        acc[mi][ni] = mfma16(af[mi], bfv[ni], acc[mi][ni]);
    __syncthreads();
    buf ^= 1;
  }

#pragma unroll
  for (int ni=0;ni<4;ni++){
    int n = n0 + wn*64 + ni*16 + li;
    float bn = bias[n];
    int hh = n >> 6, hd = n & 63;
#pragma unroll
    for (int mi=0;mi<4;mi++){
      int mb = m0 + wm*64 + mi*16 + lg*4;
#pragma unroll
      for (int j=0;j<4;j++){
        int m = mb + j;
        float val = acc[mi][ni][j] + bn;
        if (MODE == 2){
          out_f[(size_t)m*1024 + n] = val;
        } else {
          size_t idx;
          int bb = m >> 10, tp = m & 1023;
          if (MODE == 0) idx = (((size_t)(bb*16 + hh))*1024 + tp)*64 + hd;
          else           idx = (((size_t)(bb*16 + hh))*64 + hd)*1024 + tp;
          out_hi[idx] = f2bf(val);
        }
      }
    }
  }
}

// ---------------- 6: pos_k/pos_q = LN(rel) @ Wp + bp (single product) ----------------
__global__ __launch_bounds__(256) void k_pos(const us* __restrict__ reln_hi,
                                             const us* __restrict__ wt,
                                             const float* __restrict__ bpk, const float* __restrict__ bpq,
                                             us* __restrict__ posk_hi, us* __restrict__ posq_hi)
{
  int ntile = blockIdx.x;            // 0..15
  int z = blockIdx.y;                // 0: pk (weight idx 3), 1: pq (weight idx 4)
  const us* W_hi = wt + (size_t)(3 + z) * 2097152;
  const float* bias = z ? bpq : bpk;
  us* out_hi = z ? posq_hi : posk_hi;
  int t = threadIdx.x, w = t >> 6, lane = t & 63, lg = lane >> 4, li = lane & 15;
  f32x4 acc[4];
#pragma unroll
  for (int i=0;i<4;i++) acc[i] = fzero();
  int srow = w*16 + li;
  for (int kt = 0; kt < 32; kt++){
    int k0 = kt*32 + lg*8;
    bf16x8 a = *(const bf16x8*)(reln_hi + (size_t)srow*1024 + k0);
#pragma unroll
    for (int nf=0; nf<4; nf++){
      int n = ntile*64 + nf*16 + li;
      bf16x8 b = *(const bf16x8*)(W_hi + (size_t)n*1024 + k0);
      acc[nf] = mfma16(a, b, acc[nf]);
    }
  }
#pragma unroll
  for (int nf=0;nf<4;nf++){
    int n = ntile*64 + nf*16 + li;
    float bn = bias[n];
    int h = n >> 6, hd = n & 63;
#pragma unroll
    for (int j=0;j<4;j++){
      int s = w*16 + lg*4 + j;
      out_hi[(size_t)h*4096 + s*64 + hd] = f2bf(acc[nf][j] + bn);
    }
  }
}

// ---------------- 7: c2p/p2c (single product, pre-scaled by BS for exp2) ----------------
__global__ __launch_bounds__(256) void k_cp(const us* __restrict__ q_hi,
                                            const us* __restrict__ k_hi,
                                            const us* __restrict__ pk_hi,
                                            const us* __restrict__ pq_hi,
                                            us* __restrict__ c2p, us* __restrict__ p2c)
{
  int qt = blockIdx.x, bh = blockIdx.y, z = blockIdx.z;
  const us* X_hi = z ? k_hi : q_hi;
  const us* P_hi = z ? pq_hi : pk_hi;
  us* out = z ? p2c : c2p;
  int h = bh & 15;
  int t = threadIdx.x, w = t >> 6, lane = t & 63, lg = lane >> 4, li = lane & 15;
  f32x4 acc[4];
#pragma unroll
  for (int i=0;i<4;i++) acc[i] = fzero();
  size_t row = (size_t)bh*1024 + qt*64 + w*16 + li;
#pragma unroll
  for (int kk=0;kk<2;kk++){
    int k = kk*32 + lg*8;
    bf16x8 ah = *(const bf16x8*)(X_hi + row*64 + k);
#pragma unroll
    for (int nf=0;nf<4;nf++){
      int s = nf*16 + li;
      bf16x8 bh_ = *(const bf16x8*)(P_hi + (size_t)h*4096 + s*64 + k);
      acc[nf] = mfma16(ah, bh_, acc[nf]);
    }
  }
  size_t obase = ((size_t)bh*1024 + qt*64 + w*16 + lg*4) * 64;
#pragma unroll
  for (int nf=0;nf<4;nf++)
#pragma unroll
    for (int j=0;j<4;j++)
      out[obase + (size_t)j*64 + nf*16 + li] = f2bf(acc[nf][j] * BS);
}

// ---------------- 8: fused attention: 8 waves, QBLK=128, far-tile fast path ----------------
__global__ __launch_bounds__(512) void k_attn(const us* __restrict__ qhi,
                                              const us* __restrict__ khi,
                                              const us* __restrict__ vhi,
                                              const us* __restrict__ c2p, const us* __restrict__ p2c,
                                              const signed char* __restrict__ idxt,
                                              const unsigned char* __restrict__ mask,
                                              us* __restrict__ ctx_hi, us* __restrict__ ctx_lo)
{
  __shared__ __align__(16) us khi_lds[4096], vhi_lds[4096];
  __shared__ __align__(16) us c2p_lds[128*72], p2c_lds[64*72];   // padded rows: 144B stride
  __shared__ __align__(16) us p_lds[8][1024];
  __shared__ signed char idx_lds[2048];

  const int qt = blockIdx.x, bh = blockIdx.y;   // qt: 0..7
  const int b = bh >> 4, h = bh & 15;
  const int t = threadIdx.x, w = t >> 6, lane = t & 63, lg = lane >> 4, li = lane & 15;
  const int q0 = qt * 128;

  for (int i = t; i < 2047; i += 512) idx_lds[i] = idxt[i];
  {
    const us* src = c2p + ((size_t)bh*1024 + q0) * 64;
#pragma unroll
    for (int c = 0; c < 2; c++){
      int f = c*512 + t, r = f >> 3, kc = f & 7;
      *(ushort8*)&c2p_lds[r*72 + kc*8] = *(const ushort8*)(src + r*64 + kc*8);
    }
  }
  bf16x8 qfh[2];
  {
    const us* qph = qhi + ((size_t)bh*1024 + q0 + w*16 + li)*64 + lg*8;
    qfh[0] = *(const bf16x8*)(qph); qfh[1] = *(const bf16x8*)(qph + 32);
  }
  __syncthreads();
  // far-path per-row bias (scaled) for idx=0 / idx=63
  float cq0[4], cq63[4];
#pragma unroll
  for (int j=0;j<4;j++){
    int qloc = w*16 + lg*4 + j;
    cq0[j]  = b2f(c2p_lds[qloc*72 + 0]);
    cq63[j] = b2f(c2p_lds[qloc*72 + 63]);
  }

  float lrow[4];
  f32x4 accO[4];
#pragma unroll
  for (int j=0;j<4;j++){ lrow[j] = 0.f; accO[j] = fzero(); }
  const unsigned char* mptr = mask + b*1024;

  for (int kt = 0; kt < 16; kt++){
    const int k0 = kt * 64;
    const bool far = (q0 - k0 >= 192) || (k0 - q0 >= 256);
    __syncthreads();
    {  // stage K,V: one 16B chunk each per thread
      int r = t >> 3, kc = t & 7;
      *(ushort8*)&khi_lds[r*64 + ((kc ^ (r & 7))*8)] =
          *(const ushort8*)(khi + ((size_t)bh*1024 + k0 + r)*64 + kc*8);
      *(ushort8*)&vhi_lds[r*64 + ((kc ^ (r & 7))*8)] =
          *(const ushort8*)(vhi + ((size_t)bh*64 + r)*1024 + k0 + kc*8);
      if (!far)
        *(ushort8*)&p2c_lds[r*72 + kc*8] =
            *(const ushort8*)(p2c + ((size_t)bh*1024 + k0 + r)*64 + kc*8);
    }
    __syncthreads();

    // QK^T single product
    f32x4 sfr[4];
#pragma unroll
    for (int nf=0;nf<4;nf++) sfr[nf] = fzero();
#pragma unroll
    for (int kk=0; kk<2; kk++){
      int kc = kk*4 + lg;
#pragma unroll
      for (int nf=0; nf<4; nf++){
        int r = nf*16 + li;
        bf16x8 bh_ = *(const bf16x8*)&khi_lds[r*64 + ((kc ^ (r & 7))*8)];
        sfr[nf] = mfma16(qfh[kk], bh_, sfr[nf]);
      }
    }
    us* pl = &p_lds[w][0];
    if (far){
      const int cidx = (q0 > k0) ? 63 : 0;
      float cq[4];
#pragma unroll
      for (int j=0;j<4;j++) cq[j] = (q0 > k0) ? cq63[j] : cq0[j];
#pragma unroll
      for (int nf=0; nf<4; nf++){
        int kloc = nf*16 + li;
        bool mk = mptr[k0 + kloc] != 0;
        float ck = b2f(p2c[((size_t)bh*1024 + k0 + kloc)*64 + cidx]);
        int col = kloc;
#pragma unroll
        for (int j=0;j<4;j++){
          float p = mk ? 0.f : exp2f(fmaf(sfr[nf][j], QS2, cq[j] + ck));
          lrow[j] += p;
          int row = lg*4 + j;
          pl[row*64 + ((col & 7) | ((((col >> 3) ^ (row & 7))) << 3))] = f2bf(p);
        }
      }
    } else {
#pragma unroll
      for (int nf=0; nf<4; nf++){
        int kloc = nf*16 + li;
        bool mk = mptr[k0 + kloc] != 0;
        int col = kloc;
#pragma unroll
        for (int j=0;j<4;j++){
          int qloc = w*16 + lg*4 + j;
          int d = (q0 + qloc) - (k0 + kloc);
          int idx = (int)idx_lds[d + 1023];
          float s2 = fmaf(sfr[nf][j], QS2,
                          b2f(c2p_lds[qloc*72 + idx]) + b2f(p2c_lds[kloc*72 + idx]));
          float p = mk ? 0.f : exp2f(s2);
          lrow[j] += p;
          int row = lg*4 + j;
          pl[row*64 + ((col & 7) | ((((col >> 3) ^ (row & 7))) << 3))] = f2bf(p);
        }
      }
    }
    // PV single product (p_lds wave-private; same-wave DS ordering)
#pragma unroll
    for (int kk=0;kk<2;kk++){
      int kc = kk*4 + lg;
      bf16x8 af = *(const bf16x8*)((char*)pl + li*128 + ((kc ^ (li & 7)) * 16));
#pragma unroll
      for (int nf=0;nf<4;nf++){
        int r = nf*16 + li;
        bf16x8 bh_ = *(const bf16x8*)&vhi_lds[r*64 + ((kc ^ (r & 7))*8)];
        accO[nf] = mfma16(af, bh_, accO[nf]);
      }
    }
  }

  for (int o=1;o<16;o<<=1)
#pragma unroll
    for (int j=0;j<4;j++)
      lrow[j] += __shfl_xor(lrow[j], o);
#pragma unroll
  for (int nf=0;nf<4;nf++)
#pragma unroll
    for (int j=0;j<4;j++){
      int qloc = w*16 + lg*4 + j;
      float o = accO[nf][j] / lrow[j];
      size_t idx = ((size_t)(b*1024 + q0 + qloc))*1024 + h*64 + nf*16 + li;
      us hh,ll; split2(o,hh,ll);
      ctx_hi[idx] = hh; ctx_lo[idx] = ll;
    }
}

// ---------------- launch ----------------
extern "C" void kernel_launch(void* const* d_in, const int* in_sizes, int n_in,
                              void* d_out, int out_size, void* d_ws, size_t ws_size,
                              hipStream_t stream)
{
  (void)in_sizes; (void)n_in; (void)out_size; (void)ws_size;
  const float* query = (const float*)d_in[0];
  const float* kvst  = (const float*)d_in[1];
  const unsigned char* mask = (const unsigned char*)d_in[2];
  const float* Wq = (const float*)d_in[3];  const float* bq = (const float*)d_in[4];
  const float* Wk = (const float*)d_in[5];  const float* bk = (const float*)d_in[6];
  const float* Wv = (const float*)d_in[7];  const float* bv = (const float*)d_in[8];
  const float* Wo = (const float*)d_in[9];  const float* bo = (const float*)d_in[10];
  const float* rel = (const float*)d_in[11];
  const float* lng = (const float*)d_in[12]; const float* lnb = (const float*)d_in[13];
  const float* Wpk = (const float*)d_in[14]; const float* bpk = (const float*)d_in[15];
  const float* Wpq = (const float*)d_in[16]; const float* bpq = (const float*)d_in[17];

  char* ws = (char*)d_ws;
  const size_t MB = 1024*1024;
  us* Xq_hi  = (us*)(ws + 0);      us* Xq_lo  = (us*)(ws + 8*MB);
  us* vtb_hi = (us*)(ws + 0);                                        // aliases Xq (q GEMM first)
  us* Xkv_hi = (us*)(ws + 16*MB);  us* Xkv_lo = (us*)(ws + 24*MB);
  us* c2p    = (us*)(ws + 16*MB);  us* p2c    = (us*)(ws + 24*MB);   // alias Xkv after V GEMM
  us* Wt = (us*)(ws + 32*MB);                                        // 6 x (hi,lo) 2MB each
  us* ctx_hi = (us*)(ws + 32*MB);  us* ctx_lo = (us*)(ws + 40*MB);   // alias Wq/Wk after use
  us* reln_hi = (us*)(ws + 56*MB);
  us* posk_hi = (us*)(ws + 56*MB + 256*1024);
  us* posq_hi = (us*)(ws + 56*MB + 512*1024);
  signed char* idxt = (signed char*)(ws + 56*MB + 768*1024);
  us* qbuf_hi = (us*)(ws + 57*MB);
  us* kbuf_hi = (us*)(ws + 73*MB);

  k_convx<<<8192, 256, 0, stream>>>(query, kvst, Xq_hi, Xkv_hi, Xkv_lo);
  k_convw<<<dim3(32,32,6), 256, 0, stream>>>(Wq, Wk, Wv, Wpk, Wpq, Wo, Wt);
  k_lnrel<<<64, 256, 0, stream>>>(rel, lng, lnb, reln_hi);
  k_bucket<<<8, 256, 0, stream>>>(idxt);

  // Q,K: single product. V: 2 products (AhiBhi + AhiBlo).
  k_gemm<0,1><<<256, 256, 0, stream>>>(Xq_hi,  Xq_lo,  Wt + 0*2097152, Wt + 0*2097152 + 1048576, bq, qbuf_hi, nullptr);
  k_gemm<0,1><<<256, 256, 0, stream>>>(Xkv_hi, Xkv_lo, Wt + 1*2097152, Wt + 1*2097152 + 1048576, bk, kbuf_hi, nullptr);
  k_gemm<1,2><<<256, 256, 0, stream>>>(Xkv_hi, Xkv_lo, Wt + 2*2097152, Wt + 2*2097152 + 1048576, bv, vtb_hi, nullptr);

  k_pos<<<dim3(16,2), 256, 0, stream>>>(reln_hi, Wt, bpk, bpq, posk_hi, posq_hi);
  k_cp<<<dim3(16,64,2), 256, 0, stream>>>(qbuf_hi, kbuf_hi, posk_hi, posq_hi, c2p, p2c);

  k_attn<<<dim3(8,64), 512, 0, stream>>>(qbuf_hi, kbuf_hi, vtb_hi,
                                         c2p, p2c, idxt, mask, ctx_hi, ctx_lo);

  k_gemm<2,3><<<256, 256, 0, stream>>>(ctx_hi, ctx_lo, Wt + 5*2097152, Wt + 5*2097152 + 1048576, bo, nullptr, (float*)d_out);
}